// Round 6
// baseline (2206.170 us; speedup 1.0000x reference)
//
#include <hip/hip_runtime.h>
#include <hip/hip_bf16.h>

typedef __hip_bfloat16 bf16;

#define NN 30000
#define NE 480000
#define DD 128
#define ED 64
#define NH 8

// stats layout (float words) at ws offset 0
#define ST_SUM_H1 0
#define ST_SQ_H1  128
#define ST_SUM_H2 256
#define ST_SQ_H2  384
#define ST_SUM_E1 512
#define ST_SQ_E1  576
#define ST_SUM_E2 640
#define ST_SQ_E2  704
#define W_FLAG    768     // int: 1 = float inputs are bf16-packed, 0 = f32

// ws layout in 4-byte words (total 7,921,024 words = 31.7 MB)
#define W_Z     1024                  // z: N*8 f32            [zeroed]
#define W_HATT  241024                // hatt: N*128 f32       [zeroed]
#define W_SC    4081024               // score: E*8 f32
#define W_ZERO_WORDS 4081024          // stats+flag+pad+z+hatt in one memset

__device__ __forceinline__ float ldf(const void* p, long i, bool bf) {
  if (bf) return __bfloat162float(((const bf16*)p)[i]);
  return ((const float*)p)[i];
}

// dword-granular pair load of weights (i must be even). Addresses that are
// wave-uniform (loop-index-only) scalarize to s_load through the constant
// cache -> zero VMEM on the weight stream. bf16: f32 bits = u<<16 / u&hi.
template<bool BF>
__device__ __forceinline__ float2 ldw2t(const void* __restrict__ p, long i) {
  if (BF) {
    unsigned u = ((const unsigned*)p)[i >> 1];
    return make_float2(__uint_as_float(u << 16), __uint_as_float(u & 0xFFFF0000u));
  }
  return ((const float2*)p)[i >> 1];
}

// ---------------- K0: detect input dtype from x ----------------
__global__ __launch_bounds__(64) void k_detect(const void* __restrict__ x, int* __restrict__ flag)
{
  int lane = threadIdx.x;
  unsigned w = ((const unsigned*)x)[lane];
  unsigned low = w & 0xFFFFu;
  unsigned el = (low >> 7) & 0xFFu;      // bf16 exponent field of low half-word
  bool hit = (el >= 0x70u && el <= 0x86u);
  unsigned long long m = __ballot(hit);
  if (lane == 0) *flag = (__popcll(m) >= 32) ? 1 : 0;
}

// ---------------- K1: Q,K,V = x @ {Wq,Wk,Wv} -> f32 (staged in d_out) ----------------
__global__ __launch_bounds__(128) void k_qkv(
    const void* __restrict__ x, const void* __restrict__ Wq,
    const void* __restrict__ Wk, const void* __restrict__ Wv,
    float* __restrict__ Q, float* __restrict__ Kb, float* __restrict__ V,
    const int* __restrict__ flag)
{
  const bool isbf = (*flag != 0);
  __shared__ float xs[128][36];   // xs[feature][row]
  int tid = threadIdx.x;
  int row0 = blockIdx.x * 32;
  int nrows = min(32, NN - row0);
  for (int r = 0; r < 32; ++r)
    xs[tid][r] = (r < nrows) ? ldf(x, (long)(row0 + r) * DD + tid, isbf) : 0.f;
  __syncthreads();
  int c0 = (tid & 63) * 2;        // output col pair
  int rh = (tid >> 6) * 16;       // row half
  const void* Ws[3] = {Wq, Wk, Wv};
  float* Os[3] = {Q, Kb, V};
  for (int mm = 0; mm < 3; ++mm) {
    const void* W = Ws[mm];
    float u0[16], u1[16];
    #pragma unroll
    for (int r = 0; r < 16; ++r) { u0[r] = 0.f; u1[r] = 0.f; }
    #pragma unroll 4
    for (int k = 0; k < 128; ++k) {
      float w0 = ldf(W, (long)k * DD + c0, isbf);
      float w1 = ldf(W, (long)k * DD + c0 + 1, isbf);
      const float4* xp = (const float4*)&xs[k][rh];
      #pragma unroll
      for (int r4 = 0; r4 < 4; ++r4) {
        float4 x4 = xp[r4];
        u0[r4*4+0] += x4.x * w0; u1[r4*4+0] += x4.x * w1;
        u0[r4*4+1] += x4.y * w0; u1[r4*4+1] += x4.y * w1;
        u0[r4*4+2] += x4.z * w0; u1[r4*4+2] += x4.z * w1;
        u0[r4*4+3] += x4.w * w0; u1[r4*4+3] += x4.w * w1;
      }
    }
    float* O = Os[mm];
    #pragma unroll
    for (int r = 0; r < 16; ++r) {
      if (rh + r < nrows)
        *(float2*)&O[(long)(row0 + rh + r) * DD + c0] = make_float2(u0[r], u1[r]);
    }
  }
}

// ---------------- K2: per-edge scores (Pe fused), z atomic ----------------
__global__ __launch_bounds__(128) void k_edge_score(
    const int* __restrict__ ei, const void* __restrict__ ea,
    const void* __restrict__ We, const float* __restrict__ Q,
    const float* __restrict__ Kb,
    float* __restrict__ score, float* __restrict__ z,
    const int* __restrict__ flag)
{
  const bool isbf = (*flag != 0);
  __shared__ float es[64][36];    // raw ea tile [feature][edge-row]
  __shared__ int sd_s[32], sd_d[32];
  int tid = threadIdx.x;
  long e0 = (long)blockIdx.x * 32;      // NE = 32 * 15000 exactly
  #pragma unroll
  for (int i = 0; i < 16; ++i) {
    int idx = i * 128 + tid;
    es[idx & 63][idx >> 6] = ldf(ea, e0 * ED + idx, isbf);   // coalesced
  }
  if (tid < 32) sd_s[tid] = ei[e0 + tid];
  else if (tid < 64) sd_d[tid - 32] = ei[NE + e0 + (tid - 32)];
  __syncthreads();
  // Pe GEMM: pe[r] = (ea @ We)[e0+r][col=tid]
  float pe[32];
  #pragma unroll
  for (int r = 0; r < 32; ++r) pe[r] = 0.f;
  #pragma unroll 4
  for (int k = 0; k < 64; ++k) {
    float w = ldf(We, (long)k * DD + tid, isbf);
    const float4* ep = (const float4*)&es[k][0];   // LDS broadcast
    #pragma unroll
    for (int r4 = 0; r4 < 8; ++r4) {
      float4 e4 = ep[r4];
      pe[r4*4+0] += e4.x * w; pe[r4*4+1] += e4.y * w;
      pe[r4*4+2] += e4.z * w; pe[r4*4+3] += e4.w * w;
    }
  }
  int h = tid >> 4;               // head 0..7 (wave0: 0-3, wave1: 4-7)
  bool lead = (tid & 15) == 0;
  #pragma unroll 4
  for (int r = 0; r < 32; ++r) {
    int s = sd_s[r], d = sd_d[r];
    float q  = Q [(long)d * DD + tid];    // coalesced 256B per wave
    float kk = Kb[(long)s * DD + tid];
    float sv = q * kk * pe[r];
    sv += __shfl_xor(sv, 1);
    sv += __shfl_xor(sv, 2);
    sv += __shfl_xor(sv, 4);
    sv += __shfl_xor(sv, 8);              // 16-lane head reduce
    if (lead) {
      float scor = sv * 0.25f;            // 1/sqrt(16)
      score[(e0 + r) * NH + h] = scor;
      float ec = __expf(fminf(fmaxf(scor, -5.f), 5.f));
      atomicAdd(&z[(long)d * NH + h], ec);
    }
  }
}

// ---------------- K3: aggregate msg = V[src]*alpha into h_attn ----------------
__global__ __launch_bounds__(256) void k_aggregate(
    const int* __restrict__ ei, const float* __restrict__ V,
    const float* __restrict__ score, const float* __restrict__ z,
    float* __restrict__ hatt)
{
  int lane = threadIdx.x & 63;
  int wv = threadIdx.x >> 6;
  int e = blockIdx.x * 4 + wv;
  if (e >= NE) return;
  int s = ei[e], d = ei[NE + e];
  float scv = 0.f, zv = 1.f;
  if (lane < NH) { scv = score[e * NH + lane]; zv = z[d * NH + lane]; }
  float ec = __expf(fminf(fmaxf(scv, -5.f), 5.f));
  int h = lane >> 3;
  float a = __shfl(ec, h) / (__shfl(zv, h) + 1e-6f);
  float2 v = *(const float2*)(V + s * DD + 2 * lane);
  atomicAdd(&hatt[d * DD + 2 * lane], v.x * a);
  atomicAdd(&hatt[d * DD + 2 * lane + 1], v.y * a);
}

// ---------------- K4: e1 = ea + (score@W_ep + b_ep)@W_Oe + b_Oe -> d_out f32, + stats ----------------
__global__ __launch_bounds__(128) void k_edge_proj(
    const void* __restrict__ ea, const float* __restrict__ score,
    const void* __restrict__ W_ep, const void* __restrict__ b_ep,
    const void* __restrict__ W_Oe, const void* __restrict__ b_Oe,
    float* __restrict__ eout, float* __restrict__ stats,
    const int* __restrict__ flag)
{
  const bool isbf = (*flag != 0);
  __shared__ float sc[32][9];      // raw scores [edge][head]
  __shared__ float ep_lds[64][36]; // ep transposed [col][edge]
  __shared__ float rs[2][64], rq[2][64];
  int tid = threadIdx.x;
  int j = tid & 63, wv = tid >> 6, rh = wv * 16;
  float bep = ldf(b_ep, j, isbf), boe = ldf(b_Oe, j, isbf);
  float wep[8];
  #pragma unroll
  for (int hh = 0; hh < 8; ++hh) wep[hh] = ldf(W_ep, hh * ED + j, isbf);
  float lsum = 0.f, lsq = 0.f;
  for (int t = blockIdx.x; t < NE / 32; t += gridDim.x) {
    long e0 = (long)t * 32;
    __syncthreads();               // prev tile's LDS reads complete
    #pragma unroll
    for (int i = 0; i < 2; ++i) {
      int idx = i * 128 + tid;
      sc[idx >> 3][idx & 7] = score[e0 * NH + idx];   // contiguous 1KB
    }
    __syncthreads();
    // ep[r][j] = b_ep[j] + sum_h sc[r][h] * W_ep[h][j]  (rows rh..rh+15)
    float u[16];
    #pragma unroll
    for (int r = 0; r < 16; ++r) u[r] = bep;
    #pragma unroll
    for (int hh = 0; hh < 8; ++hh) {
      float w = wep[hh];
      #pragma unroll
      for (int r = 0; r < 16; ++r) u[r] += sc[rh + r][hh] * w;
    }
    #pragma unroll
    for (int r = 0; r < 16; ++r) ep_lds[j][rh + r] = u[r];
    __syncthreads();
    // out[r][j] = ea[r][j] + sum_k ep[r][k] * W_Oe[k][j] + b_Oe[j]
    float acc[16];
    #pragma unroll
    for (int r = 0; r < 16; ++r) acc[r] = 0.f;
    #pragma unroll 4
    for (int k = 0; k < 64; ++k) {
      float w = ldf(W_Oe, (long)k * ED + j, isbf);
      const float4* up = (const float4*)&ep_lds[k][rh];  // broadcast
      #pragma unroll
      for (int r4 = 0; r4 < 4; ++r4) {
        float4 u4 = up[r4];
        acc[r4*4+0] += u4.x * w; acc[r4*4+1] += u4.y * w;
        acc[r4*4+2] += u4.z * w; acc[r4*4+3] += u4.w * w;
      }
    }
    #pragma unroll
    for (int r = 0; r < 16; ++r) {
      float v = ldf(ea, (e0 + rh + r) * ED + j, isbf) + acc[r] + boe;
      eout[(e0 + rh + r) * ED + j] = v;
      lsum += v; lsq += v * v;
    }
  }
  rs[wv][j] = lsum; rq[wv][j] = lsq;
  __syncthreads();
  if (wv == 0) {
    atomicAdd(&stats[ST_SUM_E1 + j], rs[0][j] + rs[1][j]);
    atomicAdd(&stats[ST_SQ_E1 + j], rq[0][j] + rq[1][j]);
  }
}

// ---------------- K5: h1 = x + h_attn@W_Oh + b_Oh -> d_out f32, + stats ----------------
__global__ __launch_bounds__(128) void k_hproj(
    const float* __restrict__ hatt, const void* __restrict__ x,
    const void* __restrict__ W_Oh, const void* __restrict__ b_Oh,
    float* __restrict__ hout, float* __restrict__ stats,
    const int* __restrict__ flag)
{
  const bool isbf = (*flag != 0);
  __shared__ float hs[128][36];
  __shared__ float ssum[2][128], ssq[2][128];
  int tid = threadIdx.x;
  int row0 = blockIdx.x * 32;
  int nrows = min(32, NN - row0);
  for (int r = 0; r < 32; ++r)
    hs[tid][r] = (r < nrows) ? hatt[(row0 + r) * DD + tid] : 0.f;
  __syncthreads();
  int c0 = (tid & 63) * 2;
  int wv = tid >> 6;
  int rh = wv * 16;
  float u0[16], u1[16];
  #pragma unroll
  for (int r = 0; r < 16; ++r) { u0[r] = 0.f; u1[r] = 0.f; }
  #pragma unroll 4
  for (int k = 0; k < 128; ++k) {
    float w0 = ldf(W_Oh, (long)k * DD + c0, isbf);
    float w1 = ldf(W_Oh, (long)k * DD + c0 + 1, isbf);
    const float4* hp = (const float4*)&hs[k][rh];
    #pragma unroll
    for (int r4 = 0; r4 < 4; ++r4) {
      float4 h4 = hp[r4];
      u0[r4*4+0] += h4.x * w0; u1[r4*4+0] += h4.x * w1;
      u0[r4*4+1] += h4.y * w0; u1[r4*4+1] += h4.y * w1;
      u0[r4*4+2] += h4.z * w0; u1[r4*4+2] += h4.z * w1;
      u0[r4*4+3] += h4.w * w0; u1[r4*4+3] += h4.w * w1;
    }
  }
  float bo0 = ldf(b_Oh, c0, isbf), bo1 = ldf(b_Oh, c0 + 1, isbf);
  float s0 = 0.f, q0 = 0.f, s1 = 0.f, q1 = 0.f;
  #pragma unroll
  for (int r = 0; r < 16; ++r) {
    if (rh + r < nrows) {
      long row = row0 + rh + r;
      float v0 = ldf(x, row * DD + c0, isbf) + u0[r] + bo0;
      float v1 = ldf(x, row * DD + c0 + 1, isbf) + u1[r] + bo1;
      *(float2*)&hout[row * DD + c0] = make_float2(v0, v1);
      s0 += v0; q0 += v0 * v0; s1 += v1; q1 += v1 * v1;
    }
  }
  ssum[wv][c0] = s0; ssum[wv][c0 + 1] = s1;
  ssq[wv][c0] = q0;  ssq[wv][c0 + 1] = q1;
  __syncthreads();
  atomicAdd(&stats[ST_SUM_H1 + tid], ssum[0][tid] + ssum[1][tid]);
  atomicAdd(&stats[ST_SQ_H1 + tid], ssq[0][tid] + ssq[1][tid]);
}

// ---------------- K6: h BN1 + FFN + residual (in-place on d_out) + stats2 ----------------
__global__ __launch_bounds__(128) void k_hffn(
    float* __restrict__ hio,
    const void* __restrict__ g1h, const void* __restrict__ B1h,
    const void* __restrict__ W_h1, const void* __restrict__ b_h1,
    const void* __restrict__ W_h2, const void* __restrict__ b_h2,
    float* __restrict__ stats, const int* __restrict__ flag)
{
  const bool isbf = (*flag != 0);
  __shared__ float hb[128][36];   // bn1 output [feature][row]
  __shared__ float uu[256][36];   // relu hidden [feature][row]
  __shared__ float ssum[2][128], ssq[2][128];
  int tid = threadIdx.x;
  int row0 = blockIdx.x * 32;
  int nrows = min(32, NN - row0);
  float m = stats[ST_SUM_H1 + tid] * (1.0f / NN);
  float var = stats[ST_SQ_H1 + tid] * (1.0f / NN) - m * m;
  float rstd = rsqrtf(fmaxf(var, 0.f) + 1e-5f);
  float g = ldf(g1h, tid, isbf), B = ldf(B1h, tid, isbf);
  for (int r = 0; r < 32; ++r) {
    float v = (r < nrows) ? hio[(long)(row0 + r) * DD + tid] : 0.f;
    hb[tid][r] = g * (v - m) * rstd + B;
  }
  __syncthreads();
  float u0[32], u1[32];
  #pragma unroll
  for (int r = 0; r < 32; ++r) { u0[r] = 0.f; u1[r] = 0.f; }
  #pragma unroll 2
  for (int k = 0; k < 128; ++k) {
    float w0 = ldf(W_h1, (long)k * 256 + tid, isbf);
    float w1 = ldf(W_h1, (long)k * 256 + 128 + tid, isbf);
    const float4* hp = (const float4*)&hb[k][0];
    #pragma unroll
    for (int r4 = 0; r4 < 8; ++r4) {
      float4 h4 = hp[r4];
      u0[r4*4+0] += h4.x * w0; u1[r4*4+0] += h4.x * w1;
      u0[r4*4+1] += h4.y * w0; u1[r4*4+1] += h4.y * w1;
      u0[r4*4+2] += h4.z * w0; u1[r4*4+2] += h4.z * w1;
      u0[r4*4+3] += h4.w * w0; u1[r4*4+3] += h4.w * w1;
    }
  }
  float bu0 = ldf(b_h1, tid, isbf), bu1 = ldf(b_h1, 128 + tid, isbf);
  for (int r = 0; r < 32; ++r) {
    uu[tid][r]       = fmaxf(u0[r] + bu0, 0.f);
    uu[128 + tid][r] = fmaxf(u1[r] + bu1, 0.f);
  }
  __syncthreads();
  // GEMM2: cols c0, c0+1; rows rh2..rh2+15
  int c0 = (tid & 63) * 2;
  int wv2 = tid >> 6;
  int rh2 = wv2 * 16;
  float f0[16], f1[16];
  #pragma unroll
  for (int r = 0; r < 16; ++r) { f0[r] = 0.f; f1[r] = 0.f; }
  #pragma unroll 2
  for (int jj = 0; jj < 256; ++jj) {
    float w0 = ldf(W_h2, (long)jj * DD + c0, isbf);
    float w1 = ldf(W_h2, (long)jj * DD + c0 + 1, isbf);
    const float4* up = (const float4*)&uu[jj][rh2];
    #pragma unroll
    for (int r4 = 0; r4 < 4; ++r4) {
      float4 u4 = up[r4];
      f0[r4*4+0] += u4.x * w0; f1[r4*4+0] += u4.x * w1;
      f0[r4*4+1] += u4.y * w0; f1[r4*4+1] += u4.y * w1;
      f0[r4*4+2] += u4.z * w0; f1[r4*4+2] += u4.z * w1;
      f0[r4*4+3] += u4.w * w0; f1[r4*4+3] += u4.w * w1;
    }
  }
  float bf0 = ldf(b_h2, c0, isbf), bf1 = ldf(b_h2, c0 + 1, isbf);
  float s0 = 0.f, q0 = 0.f, s1 = 0.f, q1 = 0.f;
  #pragma unroll
  for (int r = 0; r < 16; ++r) {
    if (rh2 + r < nrows) {
      float t0 = hb[c0][rh2 + r] + f0[r] + bf0;
      float t1 = hb[c0 + 1][rh2 + r] + f1[r] + bf1;
      *(float2*)&hio[(long)(row0 + rh2 + r) * DD + c0] = make_float2(t0, t1);
      s0 += t0; q0 += t0 * t0; s1 += t1; q1 += t1 * t1;
    }
  }
  ssum[wv2][c0] = s0; ssum[wv2][c0 + 1] = s1;
  ssq[wv2][c0] = q0;  ssq[wv2][c0 + 1] = q1;
  __syncthreads();
  atomicAdd(&stats[ST_SUM_H2 + tid], ssum[0][tid] + ssum[1][tid]);
  atomicAdd(&stats[ST_SQ_H2 + tid], ssq[0][tid] + ssq[1][tid]);
}

// ---------------- K7: h final BN2 in-place on d_out ----------------
__global__ __launch_bounds__(256) void k_hfinal(
    float* __restrict__ io, const void* __restrict__ g,
    const void* __restrict__ B, const float* __restrict__ stats,
    const int* __restrict__ flag)
{
  const bool isbf = (*flag != 0);
  int idx = blockIdx.x * 256 + threadIdx.x;
  int c = idx & (DD - 1);
  float m = stats[ST_SUM_H2 + c] * (1.0f / NN);
  float var = stats[ST_SQ_H2 + c] * (1.0f / NN) - m * m;
  float rstd = rsqrtf(fmaxf(var, 0.f) + 1e-5f);
  float v = io[idx];
  io[idx] = ldf(g, c, isbf) * (v - m) * rstd + ldf(B, c, isbf);
}

// ---------------- K8 core: per-edge FFN with scalar (SMEM) weight stream ----------------
// Thread owns one edge. All weight addresses are loop-index-only -> wave-
// uniform -> s_load via constant cache. Edge row in XOR-swizzled LDS.
template<bool BF>
__device__ __forceinline__ void effn_core(
    const float* __restrict__ es, int tid, int sw, float* __restrict__ out,
    const void* __restrict__ W_e1, const void* __restrict__ b_e1,
    const void* __restrict__ W_e2)
{
  for (int jb = 0; jb < 16; ++jb) {     // hidden in blocks of 8
    float h[8];
    #pragma unroll
    for (int jj = 0; jj < 8; jj += 2) {
      float2 b2 = ldw2t<BF>(b_e1, jb * 8 + jj);
      h[jj] = b2.x; h[jj + 1] = b2.y;
    }
    for (int k = 0; k < 64; ++k) {
      float ek = es[tid * 64 + (k ^ sw)];          // 2-way bank alias: free
      long wb = (long)k * 128 + jb * 8;
      #pragma unroll
      for (int jj = 0; jj < 8; jj += 2) {
        float2 w = ldw2t<BF>(W_e1, wb + jj);
        h[jj]     += ek * w.x;
        h[jj + 1] += ek * w.y;
      }
    }
    #pragma unroll
    for (int jj = 0; jj < 8; ++jj) {
      float hj = fmaxf(h[jj], 0.f);
      long wb = ((long)(jb * 8 + jj)) * 64;
      #pragma unroll
      for (int c = 0; c < 64; c += 2) {
        float2 w = ldw2t<BF>(W_e2, wb + c);
        out[c]     += hj * w.x;
        out[c + 1] += hj * w.y;
      }
    }
  }
}

// ---------------- K8: e BN1 + FFN + residual (in-place on d_out) + stats2 ----------------
// v4: 1 edge/thread, 128 edges/block. v2/v3 were latency-bound on 384
// per-thread uniform VECTOR weight loads (VALUBusy 33%, all pipes idle).
// Now weights ride the scalar pipe; VMEM = staging + store only.
__global__ __launch_bounds__(128) void k_effn(
    float* __restrict__ eio,
    const void* __restrict__ g1e, const void* __restrict__ B1e,
    const void* __restrict__ W_e1, const void* __restrict__ b_e1,
    const void* __restrict__ W_e2, const void* __restrict__ b_e2,
    float* __restrict__ stats, const int* __restrict__ flag)
{
  const bool isbf = (*flag != 0);
  __shared__ float es[128 * 64];        // [row][col ^ (row&31)]  32KB
  __shared__ float ssum[2][64], ssq[2][64];
  int tid = threadIdx.x;
  int f = tid & 63;                     // feature this thread stages/stats
  int sw = tid & 31;
  long e0 = (long)blockIdx.x * 128;     // NE = 128 * 3750 exactly
  float m = stats[ST_SUM_E1 + f] * (1.0f / NE);
  float var = stats[ST_SQ_E1 + f] * (1.0f / NE) - m * m;
  float rstd = rsqrtf(fmaxf(var, 0.f) + 1e-5f);
  float g = ldf(g1e, f, isbf), B = ldf(B1e, f, isbf);
  // stage + BN1: word i = it*128+tid -> row=i>>6, col = tid&63 (constant)
  for (int it = 0; it < 64; ++it) {
    int i = it * 128 + tid;
    int row = i >> 6;
    float v = eio[e0 * ED + i];                   // coalesced
    es[row * 64 + (f ^ (row & 31))] = g * (v - m) * rstd + B;
  }
  __syncthreads();
  float out[64];
  #pragma unroll
  for (int c = 0; c < 64; ++c) out[c] = 0.f;
  if (isbf) effn_core<true >(es, tid, sw, out, W_e1, b_e1, W_e2);
  else      effn_core<false>(es, tid, sw, out, W_e1, b_e1, W_e2);
  // residual (bn1 output) + bias; rewrite own row only (no barrier needed)
  #pragma unroll
  for (int c = 0; c < 64; c += 2) {
    float2 b2 = isbf ? ldw2t<true>(b_e2, c) : ldw2t<false>(b_e2, c);
    int i0 = tid * 64 + (c ^ sw);
    int i1 = tid * 64 + ((c + 1) ^ sw);
    es[i0] = es[i0] + out[c] + b2.x;
    es[i1] = es[i1] + out[c + 1] + b2.y;
  }
  __syncthreads();
  // coalesced store + per-feature stats (thread covers 64 rows of feature f)
  float lsum = 0.f, lsq = 0.f;
  for (int it = 0; it < 64; ++it) {
    int i = it * 128 + tid;
    int row = i >> 6;
    float v = es[row * 64 + (f ^ (row & 31))];
    eio[e0 * ED + i] = v;                         // coalesced
    lsum += v; lsq += v * v;
  }
  int half = tid >> 6;
  ssum[half][f] = lsum; ssq[half][f] = lsq;
  __syncthreads();
  if (tid < 64) {
    atomicAdd(&stats[ST_SUM_E2 + tid], ssum[0][tid] + ssum[1][tid]);
    atomicAdd(&stats[ST_SQ_E2 + tid], ssq[0][tid] + ssq[1][tid]);
  }
}

// ---------------- K9: e final BN2 in-place on d_out ----------------
__global__ __launch_bounds__(256) void k_efinal(
    float* __restrict__ io, const void* __restrict__ g,
    const void* __restrict__ B, const float* __restrict__ stats,
    const int* __restrict__ flag)
{
  const bool isbf = (*flag != 0);
  int idx = blockIdx.x * 256 + threadIdx.x;
  int c = idx & (ED - 1);
  float m = stats[ST_SUM_E2 + c] * (1.0f / NE);
  float var = stats[ST_SQ_E2 + c] * (1.0f / NE) - m * m;
  float rstd = rsqrtf(fmaxf(var, 0.f) + 1e-5f);
  float v = io[idx];
  io[idx] = ldf(g, c, isbf) * (v - m) * rstd + ldf(B, c, isbf);
}

extern "C" void kernel_launch(void* const* d_in, const int* in_sizes, int n_in,
                              void* d_out, int out_size, void* d_ws, size_t ws_size,
                              hipStream_t stream) {
  const void* x    = d_in[0];
  const int*  ei   = (const int*)d_in[1];
  const void* ea   = d_in[2];
  const void* Wq   = d_in[3];
  const void* Wk   = d_in[4];
  const void* Wv   = d_in[5];
  const void* We   = d_in[6];
  const void* W_Oh = d_in[7];
  const void* b_Oh = d_in[8];
  const void* W_ep = d_in[9];
  const void* b_ep = d_in[10];
  const void* W_Oe = d_in[11];
  const void* b_Oe = d_in[12];
  const void* W_h1 = d_in[13];
  const void* b_h1 = d_in[14];
  const void* W_h2 = d_in[15];
  const void* b_h2 = d_in[16];
  const void* W_e1 = d_in[17];
  const void* b_e1 = d_in[18];
  const void* W_e2 = d_in[19];
  const void* b_e2 = d_in[20];
  const void* g1h  = d_in[21];
  const void* B1h  = d_in[22];
  const void* g1e  = d_in[23];
  const void* B1e  = d_in[24];
  const void* g2h  = d_in[25];
  const void* B2h  = d_in[26];
  const void* g2e  = d_in[27];
  const void* B2e  = d_in[28];

  float* ws    = (float*)d_ws;
  float* stats = ws;                  // 768 fl + flag
  int*   flag  = (int*)(ws + W_FLAG);
  float* z     = ws + W_Z;            // N*8 fl   [zeroed]
  float* hatt  = ws + W_HATT;         // N*128 fl [zeroed]
  float* score = ws + W_SC;           // E*8 f32
  // ws total: 31.7 MB

  // Q/K/V staged inside d_out (consumed by k_aggregate before being overwritten)
  float* out  = (float*)d_out;           // 34.56M f32 total
  float* hout = out;                     // N*128 (h staging + final)
  float* eout = out + (size_t)NN * DD;   // E*64 (e staging + final)
  float* Q    = out;                     // [0, 3.84M)
  float* Kb   = out + 3840000;           // [3.84M, 7.68M)
  float* V    = out + 7680000;           // [7.68M, 11.52M)

  hipMemsetAsync(ws, 0, (size_t)W_ZERO_WORDS * sizeof(float), stream);
  k_detect<<<1, 64, 0, stream>>>(x, flag);

  k_qkv<<<938, 128, 0, stream>>>(x, Wq, Wk, Wv, Q, Kb, V, flag);
  k_edge_score<<<15000, 128, 0, stream>>>(ei, ea, We, Q, Kb, score, z, flag);
  k_aggregate<<<120000, 256, 0, stream>>>(ei, V, score, z, hatt);
  k_edge_proj<<<2048, 128, 0, stream>>>(ea, score, W_ep, b_ep, W_Oe, b_Oe, eout, stats, flag);
  k_hproj<<<938, 128, 0, stream>>>(hatt, x, W_Oh, b_Oh, hout, stats, flag);
  k_hffn<<<938, 128, 0, stream>>>(hout, g1h, B1h, W_h1, b_h1, W_h2, b_h2, stats, flag);
  k_hfinal<<<15000, 256, 0, stream>>>(hout, g2h, B2h, stats, flag);
  k_effn<<<3750, 128, 0, stream>>>(eout, g1e, B1e, W_e1, b_e1, W_e2, b_e2, stats, flag);
  k_efinal<<<120000, 256, 0, stream>>>(eout, g2e, B2e, stats, flag);
}

// Round 8
// 2055.280 us; speedup vs baseline: 1.0734x; 1.0734x over previous
//
#include <hip/hip_runtime.h>
#include <hip/hip_bf16.h>

typedef __hip_bfloat16 bf16;

#define NN 30000
#define NE 480000
#define DD 128
#define ED 64
#define NH 8

// stats layout (float words) at ws offset 0
#define ST_SUM_H1 0
#define ST_SQ_H1  128
#define ST_SUM_H2 256
#define ST_SQ_H2  384
#define ST_SUM_E1 512
#define ST_SQ_E1  576
#define ST_SUM_E2 640
#define ST_SQ_E2  704
#define W_FLAG    768     // int: 1 = float inputs are bf16-packed, 0 = f32

// ws layout in 4-byte words (total 7,921,024 words = 31.7 MB)
#define W_Z     1024                  // z: N*8 f32            [zeroed]
#define W_HATT  241024                // hatt: N*128 f32       [zeroed]
#define W_SC    4081024               // score: E*8 f32
#define W_ZERO_WORDS 4081024          // stats+flag+pad+z+hatt in one memset

__device__ __forceinline__ float ldf(const void* p, long i, bool bf) {
  if (bf) return __bfloat162float(((const bf16*)p)[i]);
  return ((const float*)p)[i];
}

// ---------------- K0: detect input dtype from x ----------------
__global__ __launch_bounds__(64) void k_detect(const void* __restrict__ x, int* __restrict__ flag)
{
  int lane = threadIdx.x;
  unsigned w = ((const unsigned*)x)[lane];
  unsigned low = w & 0xFFFFu;
  unsigned el = (low >> 7) & 0xFFu;      // bf16 exponent field of low half-word
  bool hit = (el >= 0x70u && el <= 0x86u);
  unsigned long long m = __ballot(hit);
  if (lane == 0) *flag = (__popcll(m) >= 32) ? 1 : 0;
}

// ---------------- K1: Q,K,V = x @ {Wq,Wk,Wv} -> f32 (staged in d_out) ----------------
__global__ __launch_bounds__(128) void k_qkv(
    const void* __restrict__ x, const void* __restrict__ Wq,
    const void* __restrict__ Wk, const void* __restrict__ Wv,
    float* __restrict__ Q, float* __restrict__ Kb, float* __restrict__ V,
    const int* __restrict__ flag)
{
  const bool isbf = (*flag != 0);
  __shared__ float xs[128][36];   // xs[feature][row]
  int tid = threadIdx.x;
  int row0 = blockIdx.x * 32;
  int nrows = min(32, NN - row0);
  for (int r = 0; r < 32; ++r)
    xs[tid][r] = (r < nrows) ? ldf(x, (long)(row0 + r) * DD + tid, isbf) : 0.f;
  __syncthreads();
  int c0 = (tid & 63) * 2;        // output col pair
  int rh = (tid >> 6) * 16;       // row half
  const void* Ws[3] = {Wq, Wk, Wv};
  float* Os[3] = {Q, Kb, V};
  for (int mm = 0; mm < 3; ++mm) {
    const void* W = Ws[mm];
    float u0[16], u1[16];
    #pragma unroll
    for (int r = 0; r < 16; ++r) { u0[r] = 0.f; u1[r] = 0.f; }
    #pragma unroll 4
    for (int k = 0; k < 128; ++k) {
      float w0 = ldf(W, (long)k * DD + c0, isbf);
      float w1 = ldf(W, (long)k * DD + c0 + 1, isbf);
      const float4* xp = (const float4*)&xs[k][rh];
      #pragma unroll
      for (int r4 = 0; r4 < 4; ++r4) {
        float4 x4 = xp[r4];
        u0[r4*4+0] += x4.x * w0; u1[r4*4+0] += x4.x * w1;
        u0[r4*4+1] += x4.y * w0; u1[r4*4+1] += x4.y * w1;
        u0[r4*4+2] += x4.z * w0; u1[r4*4+2] += x4.z * w1;
        u0[r4*4+3] += x4.w * w0; u1[r4*4+3] += x4.w * w1;
      }
    }
    float* O = Os[mm];
    #pragma unroll
    for (int r = 0; r < 16; ++r) {
      if (rh + r < nrows)
        *(float2*)&O[(long)(row0 + rh + r) * DD + c0] = make_float2(u0[r], u1[r]);
    }
  }
}

// ---------------- K2: per-edge scores (Pe fused), z atomic ----------------
__global__ __launch_bounds__(128) void k_edge_score(
    const int* __restrict__ ei, const void* __restrict__ ea,
    const void* __restrict__ We, const float* __restrict__ Q,
    const float* __restrict__ Kb,
    float* __restrict__ score, float* __restrict__ z,
    const int* __restrict__ flag)
{
  const bool isbf = (*flag != 0);
  __shared__ float es[64][36];    // raw ea tile [feature][edge-row]
  __shared__ int sd_s[32], sd_d[32];
  int tid = threadIdx.x;
  long e0 = (long)blockIdx.x * 32;      // NE = 32 * 15000 exactly
  #pragma unroll
  for (int i = 0; i < 16; ++i) {
    int idx = i * 128 + tid;
    es[idx & 63][idx >> 6] = ldf(ea, e0 * ED + idx, isbf);   // coalesced
  }
  if (tid < 32) sd_s[tid] = ei[e0 + tid];
  else if (tid < 64) sd_d[tid - 32] = ei[NE + e0 + (tid - 32)];
  __syncthreads();
  // Pe GEMM: pe[r] = (ea @ We)[e0+r][col=tid]
  float pe[32];
  #pragma unroll
  for (int r = 0; r < 32; ++r) pe[r] = 0.f;
  #pragma unroll 4
  for (int k = 0; k < 64; ++k) {
    float w = ldf(We, (long)k * DD + tid, isbf);
    const float4* ep = (const float4*)&es[k][0];   // LDS broadcast
    #pragma unroll
    for (int r4 = 0; r4 < 8; ++r4) {
      float4 e4 = ep[r4];
      pe[r4*4+0] += e4.x * w; pe[r4*4+1] += e4.y * w;
      pe[r4*4+2] += e4.z * w; pe[r4*4+3] += e4.w * w;
    }
  }
  int h = tid >> 4;               // head 0..7 (wave0: 0-3, wave1: 4-7)
  bool lead = (tid & 15) == 0;
  #pragma unroll 4
  for (int r = 0; r < 32; ++r) {
    int s = sd_s[r], d = sd_d[r];
    float q  = Q [(long)d * DD + tid];    // coalesced 256B per wave
    float kk = Kb[(long)s * DD + tid];
    float sv = q * kk * pe[r];
    sv += __shfl_xor(sv, 1);
    sv += __shfl_xor(sv, 2);
    sv += __shfl_xor(sv, 4);
    sv += __shfl_xor(sv, 8);              // 16-lane head reduce
    if (lead) {
      float scor = sv * 0.25f;            // 1/sqrt(16)
      score[(e0 + r) * NH + h] = scor;
      float ec = __expf(fminf(fmaxf(scor, -5.f), 5.f));
      atomicAdd(&z[(long)d * NH + h], ec);
    }
  }
}

// ---------------- K3: aggregate msg = V[src]*alpha into h_attn ----------------
__global__ __launch_bounds__(256) void k_aggregate(
    const int* __restrict__ ei, const float* __restrict__ V,
    const float* __restrict__ score, const float* __restrict__ z,
    float* __restrict__ hatt)
{
  int lane = threadIdx.x & 63;
  int wv = threadIdx.x >> 6;
  int e = blockIdx.x * 4 + wv;
  if (e >= NE) return;
  int s = ei[e], d = ei[NE + e];
  float scv = 0.f, zv = 1.f;
  if (lane < NH) { scv = score[e * NH + lane]; zv = z[d * NH + lane]; }
  float ec = __expf(fminf(fmaxf(scv, -5.f), 5.f));
  int h = lane >> 3;
  float a = __shfl(ec, h) / (__shfl(zv, h) + 1e-6f);
  float2 v = *(const float2*)(V + s * DD + 2 * lane);
  atomicAdd(&hatt[d * DD + 2 * lane], v.x * a);
  atomicAdd(&hatt[d * DD + 2 * lane + 1], v.y * a);
}

// ---------------- K4: e1 = ea + (score@W_ep + b_ep)@W_Oe + b_Oe -> d_out f32, + stats ----------------
__global__ __launch_bounds__(128) void k_edge_proj(
    const void* __restrict__ ea, const float* __restrict__ score,
    const void* __restrict__ W_ep, const void* __restrict__ b_ep,
    const void* __restrict__ W_Oe, const void* __restrict__ b_Oe,
    float* __restrict__ eout, float* __restrict__ stats,
    const int* __restrict__ flag)
{
  const bool isbf = (*flag != 0);
  __shared__ float sc[32][9];      // raw scores [edge][head]
  __shared__ float ep_lds[64][36]; // ep transposed [col][edge]
  __shared__ float rs[2][64], rq[2][64];
  int tid = threadIdx.x;
  int j = tid & 63, wv = tid >> 6, rh = wv * 16;
  float bep = ldf(b_ep, j, isbf), boe = ldf(b_Oe, j, isbf);
  float wep[8];
  #pragma unroll
  for (int hh = 0; hh < 8; ++hh) wep[hh] = ldf(W_ep, hh * ED + j, isbf);
  float lsum = 0.f, lsq = 0.f;
  for (int t = blockIdx.x; t < NE / 32; t += gridDim.x) {
    long e0 = (long)t * 32;
    __syncthreads();               // prev tile's LDS reads complete
    #pragma unroll
    for (int i = 0; i < 2; ++i) {
      int idx = i * 128 + tid;
      sc[idx >> 3][idx & 7] = score[e0 * NH + idx];   // contiguous 1KB
    }
    __syncthreads();
    // ep[r][j] = b_ep[j] + sum_h sc[r][h] * W_ep[h][j]  (rows rh..rh+15)
    float u[16];
    #pragma unroll
    for (int r = 0; r < 16; ++r) u[r] = bep;
    #pragma unroll
    for (int hh = 0; hh < 8; ++hh) {
      float w = wep[hh];
      #pragma unroll
      for (int r = 0; r < 16; ++r) u[r] += sc[rh + r][hh] * w;
    }
    #pragma unroll
    for (int r = 0; r < 16; ++r) ep_lds[j][rh + r] = u[r];
    __syncthreads();
    // out[r][j] = ea[r][j] + sum_k ep[r][k] * W_Oe[k][j] + b_Oe[j]
    float acc[16];
    #pragma unroll
    for (int r = 0; r < 16; ++r) acc[r] = 0.f;
    #pragma unroll 4
    for (int k = 0; k < 64; ++k) {
      float w = ldf(W_Oe, (long)k * ED + j, isbf);
      const float4* up = (const float4*)&ep_lds[k][rh];  // broadcast
      #pragma unroll
      for (int r4 = 0; r4 < 4; ++r4) {
        float4 u4 = up[r4];
        acc[r4*4+0] += u4.x * w; acc[r4*4+1] += u4.y * w;
        acc[r4*4+2] += u4.z * w; acc[r4*4+3] += u4.w * w;
      }
    }
    #pragma unroll
    for (int r = 0; r < 16; ++r) {
      float v = ldf(ea, (e0 + rh + r) * ED + j, isbf) + acc[r] + boe;
      eout[(e0 + rh + r) * ED + j] = v;
      lsum += v; lsq += v * v;
    }
  }
  rs[wv][j] = lsum; rq[wv][j] = lsq;
  __syncthreads();
  if (wv == 0) {
    atomicAdd(&stats[ST_SUM_E1 + j], rs[0][j] + rs[1][j]);
    atomicAdd(&stats[ST_SQ_E1 + j], rq[0][j] + rq[1][j]);
  }
}

// ---------------- K5: h1 = x + h_attn@W_Oh + b_Oh -> d_out f32, + stats ----------------
__global__ __launch_bounds__(128) void k_hproj(
    const float* __restrict__ hatt, const void* __restrict__ x,
    const void* __restrict__ W_Oh, const void* __restrict__ b_Oh,
    float* __restrict__ hout, float* __restrict__ stats,
    const int* __restrict__ flag)
{
  const bool isbf = (*flag != 0);
  __shared__ float hs[128][36];
  __shared__ float ssum[2][128], ssq[2][128];
  int tid = threadIdx.x;
  int row0 = blockIdx.x * 32;
  int nrows = min(32, NN - row0);
  for (int r = 0; r < 32; ++r)
    hs[tid][r] = (r < nrows) ? hatt[(row0 + r) * DD + tid] : 0.f;
  __syncthreads();
  int c0 = (tid & 63) * 2;
  int wv = tid >> 6;
  int rh = wv * 16;
  float u0[16], u1[16];
  #pragma unroll
  for (int r = 0; r < 16; ++r) { u0[r] = 0.f; u1[r] = 0.f; }
  #pragma unroll 4
  for (int k = 0; k < 128; ++k) {
    float w0 = ldf(W_Oh, (long)k * DD + c0, isbf);
    float w1 = ldf(W_Oh, (long)k * DD + c0 + 1, isbf);
    const float4* hp = (const float4*)&hs[k][rh];
    #pragma unroll
    for (int r4 = 0; r4 < 4; ++r4) {
      float4 h4 = hp[r4];
      u0[r4*4+0] += h4.x * w0; u1[r4*4+0] += h4.x * w1;
      u0[r4*4+1] += h4.y * w0; u1[r4*4+1] += h4.y * w1;
      u0[r4*4+2] += h4.z * w0; u1[r4*4+2] += h4.z * w1;
      u0[r4*4+3] += h4.w * w0; u1[r4*4+3] += h4.w * w1;
    }
  }
  float bo0 = ldf(b_Oh, c0, isbf), bo1 = ldf(b_Oh, c0 + 1, isbf);
  float s0 = 0.f, q0 = 0.f, s1 = 0.f, q1 = 0.f;
  #pragma unroll
  for (int r = 0; r < 16; ++r) {
    if (rh + r < nrows) {
      long row = row0 + rh + r;
      float v0 = ldf(x, row * DD + c0, isbf) + u0[r] + bo0;
      float v1 = ldf(x, row * DD + c0 + 1, isbf) + u1[r] + bo1;
      *(float2*)&hout[row * DD + c0] = make_float2(v0, v1);
      s0 += v0; q0 += v0 * v0; s1 += v1; q1 += v1 * v1;
    }
  }
  ssum[wv][c0] = s0; ssum[wv][c0 + 1] = s1;
  ssq[wv][c0] = q0;  ssq[wv][c0 + 1] = q1;
  __syncthreads();
  atomicAdd(&stats[ST_SUM_H1 + tid], ssum[0][tid] + ssum[1][tid]);
  atomicAdd(&stats[ST_SQ_H1 + tid], ssq[0][tid] + ssq[1][tid]);
}

// ---------------- K6: h BN1 + FFN + residual (in-place on d_out) + stats2 ----------------
__global__ __launch_bounds__(128) void k_hffn(
    float* __restrict__ hio,
    const void* __restrict__ g1h, const void* __restrict__ B1h,
    const void* __restrict__ W_h1, const void* __restrict__ b_h1,
    const void* __restrict__ W_h2, const void* __restrict__ b_h2,
    float* __restrict__ stats, const int* __restrict__ flag)
{
  const bool isbf = (*flag != 0);
  __shared__ float hb[128][36];   // bn1 output [feature][row]
  __shared__ float uu[256][36];   // relu hidden [feature][row]
  __shared__ float ssum[2][128], ssq[2][128];
  int tid = threadIdx.x;
  int row0 = blockIdx.x * 32;
  int nrows = min(32, NN - row0);
  float m = stats[ST_SUM_H1 + tid] * (1.0f / NN);
  float var = stats[ST_SQ_H1 + tid] * (1.0f / NN) - m * m;
  float rstd = rsqrtf(fmaxf(var, 0.f) + 1e-5f);
  float g = ldf(g1h, tid, isbf), B = ldf(B1h, tid, isbf);
  for (int r = 0; r < 32; ++r) {
    float v = (r < nrows) ? hio[(long)(row0 + r) * DD + tid] : 0.f;
    hb[tid][r] = g * (v - m) * rstd + B;
  }
  __syncthreads();
  float u0[32], u1[32];
  #pragma unroll
  for (int r = 0; r < 32; ++r) { u0[r] = 0.f; u1[r] = 0.f; }
  #pragma unroll 2
  for (int k = 0; k < 128; ++k) {
    float w0 = ldf(W_h1, (long)k * 256 + tid, isbf);
    float w1 = ldf(W_h1, (long)k * 256 + 128 + tid, isbf);
    const float4* hp = (const float4*)&hb[k][0];
    #pragma unroll
    for (int r4 = 0; r4 < 8; ++r4) {
      float4 h4 = hp[r4];
      u0[r4*4+0] += h4.x * w0; u1[r4*4+0] += h4.x * w1;
      u0[r4*4+1] += h4.y * w0; u1[r4*4+1] += h4.y * w1;
      u0[r4*4+2] += h4.z * w0; u1[r4*4+2] += h4.z * w1;
      u0[r4*4+3] += h4.w * w0; u1[r4*4+3] += h4.w * w1;
    }
  }
  float bu0 = ldf(b_h1, tid, isbf), bu1 = ldf(b_h1, 128 + tid, isbf);
  for (int r = 0; r < 32; ++r) {
    uu[tid][r]       = fmaxf(u0[r] + bu0, 0.f);
    uu[128 + tid][r] = fmaxf(u1[r] + bu1, 0.f);
  }
  __syncthreads();
  // GEMM2: cols c0, c0+1; rows rh2..rh2+15
  int c0 = (tid & 63) * 2;
  int wv2 = tid >> 6;
  int rh2 = wv2 * 16;
  float f0[16], f1[16];
  #pragma unroll
  for (int r = 0; r < 16; ++r) { f0[r] = 0.f; f1[r] = 0.f; }
  #pragma unroll 2
  for (int jj = 0; jj < 256; ++jj) {
    float w0 = ldf(W_h2, (long)jj * DD + c0, isbf);
    float w1 = ldf(W_h2, (long)jj * DD + c0 + 1, isbf);
    const float4* up = (const float4*)&uu[jj][rh2];
    #pragma unroll
    for (int r4 = 0; r4 < 4; ++r4) {
      float4 u4 = up[r4];
      f0[r4*4+0] += u4.x * w0; f1[r4*4+0] += u4.x * w1;
      f0[r4*4+1] += u4.y * w0; f1[r4*4+1] += u4.y * w1;
      f0[r4*4+2] += u4.z * w0; f1[r4*4+2] += u4.z * w1;
      f0[r4*4+3] += u4.w * w0; f1[r4*4+3] += u4.w * w1;
    }
  }
  float bf0 = ldf(b_h2, c0, isbf), bf1 = ldf(b_h2, c0 + 1, isbf);
  float s0 = 0.f, q0 = 0.f, s1 = 0.f, q1 = 0.f;
  #pragma unroll
  for (int r = 0; r < 16; ++r) {
    if (rh2 + r < nrows) {
      float t0 = hb[c0][rh2 + r] + f0[r] + bf0;
      float t1 = hb[c0 + 1][rh2 + r] + f1[r] + bf1;
      *(float2*)&hio[(long)(row0 + rh2 + r) * DD + c0] = make_float2(t0, t1);
      s0 += t0; q0 += t0 * t0; s1 += t1; q1 += t1 * t1;
    }
  }
  ssum[wv2][c0] = s0; ssum[wv2][c0 + 1] = s1;
  ssq[wv2][c0] = q0;  ssq[wv2][c0 + 1] = q1;
  __syncthreads();
  atomicAdd(&stats[ST_SUM_H2 + tid], ssum[0][tid] + ssum[1][tid]);
  atomicAdd(&stats[ST_SQ_H2 + tid], ssq[0][tid] + ssq[1][tid]);
}

// ---------------- K7: h final BN2 in-place on d_out ----------------
__global__ __launch_bounds__(256) void k_hfinal(
    float* __restrict__ io, const void* __restrict__ g,
    const void* __restrict__ B, const float* __restrict__ stats,
    const int* __restrict__ flag)
{
  const bool isbf = (*flag != 0);
  int idx = blockIdx.x * 256 + threadIdx.x;
  int c = idx & (DD - 1);
  float m = stats[ST_SUM_H2 + c] * (1.0f / NN);
  float var = stats[ST_SQ_H2 + c] * (1.0f / NN) - m * m;
  float rstd = rsqrtf(fmaxf(var, 0.f) + 1e-5f);
  float v = io[idx];
  io[idx] = ldf(g, c, isbf) * (v - m) * rstd + ldf(B, c, isbf);
}

// ---------------- K8: e BN1 + FFN + residual (in-place on d_out) + stats2 ----------------
// v5: v2 structure (best measured, 427us) + hidden chunked 2x64 through one
// uu[64][36] buffer -> LDS 28.7KB -> 19.5KB -> 8 blocks/CU (occupancy 26->50%).
// v2/v3/v4 evidence: wave-starved (VALUBusy ~32% at 26% occ), not pipe-bound.
__global__ __launch_bounds__(128) void k_effn(
    float* __restrict__ eio,
    const void* __restrict__ g1e, const void* __restrict__ B1e,
    const void* __restrict__ W_e1, const void* __restrict__ b_e1,
    const void* __restrict__ W_e2, const void* __restrict__ b_e2,
    float* __restrict__ stats, const int* __restrict__ flag)
{
  const bool isbf = (*flag != 0);
  __shared__ float es[64][36];    // bn1 output [feature][row]   9216B
  __shared__ float uu[64][36];    // relu hidden chunk [j][row]  9216B
  __shared__ float ssum[2][64], ssq[2][64];
  int tid = threadIdx.x;
  int f = tid & 63;               // feature / hidden col / out col
  int wv = tid >> 6;              // wave id
  int rh = wv * 16;               // row half
  long row0 = (long)blockIdx.x * 32;   // NE = 32 * 15000 exactly
  float m = stats[ST_SUM_E1 + f] * (1.0f / NE);
  float var = stats[ST_SQ_E1 + f] * (1.0f / NE) - m * m;
  float rstd = rsqrtf(fmaxf(var, 0.f) + 1e-5f);
  float g = ldf(g1e, f, isbf), B = ldf(B1e, f, isbf);
  #pragma unroll
  for (int r = 0; r < 16; ++r) {
    float v = eio[(row0 + rh + r) * ED + f];     // coalesced across lanes
    es[f][rh + r] = g * (v - m) * rstd + B;
  }
  __syncthreads();
  float acc[16];                  // GEMM2 accumulator across both chunks
  #pragma unroll
  for (int r = 0; r < 16; ++r) acc[r] = 0.f;
  for (int ch = 0; ch < 2; ++ch) {
    // GEMM1: hidden col j = ch*64+f, rows rh..rh+15 (reads es only)
    float u[16];
    #pragma unroll
    for (int r = 0; r < 16; ++r) u[r] = 0.f;
    #pragma unroll 4
    for (int k = 0; k < 64; ++k) {
      float w = ldf(W_e1, (long)k * 128 + ch * 64 + f, isbf);
      const float4* ep = (const float4*)&es[k][rh];   // broadcast
      #pragma unroll
      for (int r4 = 0; r4 < 4; ++r4) {
        float4 e4 = ep[r4];
        u[r4*4+0] += e4.x * w; u[r4*4+1] += e4.y * w;
        u[r4*4+2] += e4.z * w; u[r4*4+3] += e4.w * w;
      }
    }
    __syncthreads();              // prev chunk's uu reads done before rewrite
    float bu = ldf(b_e1, ch * 64 + f, isbf);
    for (int r = 0; r < 16; ++r) uu[f][rh + r] = fmaxf(u[r] + bu, 0.f);
    __syncthreads();
    // GEMM2 partial: out col f, rows rh..rh+15, hidden jj in this chunk
    #pragma unroll 4
    for (int jj = 0; jj < 64; ++jj) {
      float w = ldf(W_e2, (long)(ch * 64 + jj) * ED + f, isbf);
      const float4* up = (const float4*)&uu[jj][rh];  // broadcast
      #pragma unroll
      for (int r4 = 0; r4 < 4; ++r4) {
        float4 u4 = up[r4];
        acc[r4*4+0] += u4.x * w; acc[r4*4+1] += u4.y * w;
        acc[r4*4+2] += u4.z * w; acc[r4*4+3] += u4.w * w;
      }
    }
  }
  float bf2 = ldf(b_e2, f, isbf);
  float lsum = 0.f, lsq = 0.f;
  #pragma unroll
  for (int r = 0; r < 16; ++r) {
    float t = es[f][rh + r] + acc[r] + bf2;        // residual on bn1 output
    eio[(row0 + rh + r) * ED + f] = t;             // coalesced
    lsum += t; lsq += t * t;
  }
  ssum[wv][f] = lsum; ssq[wv][f] = lsq;
  __syncthreads();
  if (tid < 64) {
    atomicAdd(&stats[ST_SUM_E2 + tid], ssum[0][tid] + ssum[1][tid]);
    atomicAdd(&stats[ST_SQ_E2 + tid], ssq[0][tid] + ssq[1][tid]);
  }
}

// ---------------- K9: e final BN2 in-place on d_out ----------------
__global__ __launch_bounds__(256) void k_efinal(
    float* __restrict__ io, const void* __restrict__ g,
    const void* __restrict__ B, const float* __restrict__ stats,
    const int* __restrict__ flag)
{
  const bool isbf = (*flag != 0);
  int idx = blockIdx.x * 256 + threadIdx.x;
  int c = idx & (ED - 1);
  float m = stats[ST_SUM_E2 + c] * (1.0f / NE);
  float var = stats[ST_SQ_E2 + c] * (1.0f / NE) - m * m;
  float rstd = rsqrtf(fmaxf(var, 0.f) + 1e-5f);
  float v = io[idx];
  io[idx] = ldf(g, c, isbf) * (v - m) * rstd + ldf(B, c, isbf);
}

extern "C" void kernel_launch(void* const* d_in, const int* in_sizes, int n_in,
                              void* d_out, int out_size, void* d_ws, size_t ws_size,
                              hipStream_t stream) {
  const void* x    = d_in[0];
  const int*  ei   = (const int*)d_in[1];
  const void* ea   = d_in[2];
  const void* Wq   = d_in[3];
  const void* Wk   = d_in[4];
  const void* Wv   = d_in[5];
  const void* We   = d_in[6];
  const void* W_Oh = d_in[7];
  const void* b_Oh = d_in[8];
  const void* W_ep = d_in[9];
  const void* b_ep = d_in[10];
  const void* W_Oe = d_in[11];
  const void* b_Oe = d_in[12];
  const void* W_h1 = d_in[13];
  const void* b_h1 = d_in[14];
  const void* W_h2 = d_in[15];
  const void* b_h2 = d_in[16];
  const void* W_e1 = d_in[17];
  const void* b_e1 = d_in[18];
  const void* W_e2 = d_in[19];
  const void* b_e2 = d_in[20];
  const void* g1h  = d_in[21];
  const void* B1h  = d_in[22];
  const void* g1e  = d_in[23];
  const void* B1e  = d_in[24];
  const void* g2h  = d_in[25];
  const void* B2h  = d_in[26];
  const void* g2e  = d_in[27];
  const void* B2e  = d_in[28];

  float* ws    = (float*)d_ws;
  float* stats = ws;                  // 768 fl + flag
  int*   flag  = (int*)(ws + W_FLAG);
  float* z     = ws + W_Z;            // N*8 fl   [zeroed]
  float* hatt  = ws + W_HATT;         // N*128 fl [zeroed]
  float* score = ws + W_SC;           // E*8 f32
  // ws total: 31.7 MB

  // Q/K/V staged inside d_out (consumed by k_aggregate before being overwritten)
  float* out  = (float*)d_out;           // 34.56M f32 total
  float* hout = out;                     // N*128 (h staging + final)
  float* eout = out + (size_t)NN * DD;   // E*64 (e staging + final)
  float* Q    = out;                     // [0, 3.84M)
  float* Kb   = out + 3840000;           // [3.84M, 7.68M)
  float* V    = out + 7680000;           // [7.68M, 11.52M)

  hipMemsetAsync(ws, 0, (size_t)W_ZERO_WORDS * sizeof(float), stream);
  k_detect<<<1, 64, 0, stream>>>(x, flag);

  k_qkv<<<938, 128, 0, stream>>>(x, Wq, Wk, Wv, Q, Kb, V, flag);
  k_edge_score<<<15000, 128, 0, stream>>>(ei, ea, We, Q, Kb, score, z, flag);
  k_aggregate<<<120000, 256, 0, stream>>>(ei, V, score, z, hatt);
  k_edge_proj<<<2048, 128, 0, stream>>>(ea, score, W_ep, b_ep, W_Oe, b_Oe, eout, stats, flag);
  k_hproj<<<938, 128, 0, stream>>>(hatt, x, W_Oh, b_Oh, hout, stats, flag);
  k_hffn<<<938, 128, 0, stream>>>(hout, g1h, B1h, W_h1, b_h1, W_h2, b_h2, stats, flag);
  k_hfinal<<<15000, 256, 0, stream>>>(hout, g2h, B2h, stats, flag);
  k_effn<<<15000, 128, 0, stream>>>(eout, g1e, B1e, W_e1, b_e1, W_e2, b_e2, stats, flag);
  k_efinal<<<120000, 256, 0, stream>>>(eout, g2e, B2e, stats, flag);
}

// Round 10
// 1830.219 us; speedup vs baseline: 1.2054x; 1.1230x over previous
//
#include <hip/hip_runtime.h>
#include <hip/hip_bf16.h>

typedef __hip_bfloat16 bf16;

#define NN 30000
#define NE 480000
#define DD 128
#define ED 64
#define NH 8

#define ST_SUM_H1 0
#define ST_SQ_H1  128
#define ST_SUM_H2 256
#define ST_SQ_H2  384
#define ST_SUM_E1 512
#define ST_SQ_E1  576
#define ST_SUM_E2 640
#define ST_SQ_E2  704
#define W_FLAG    768

#define W_HATT  241024                // hatt: N*128 f32 in ws (fully written, no memset)
#define W_SC    4081024               // score: E*8 f32 in ws

// d_out scratch (float offsets) — alive only until k_aggregate completes;
// eout [3.84M,34.56M) overwrites this AFTER aggregate (k_edge_proj onward).
#define CSR_DEG   12000000
#define CSR_ROW   12030000            // 30001 ints
#define CSR_CUR   12060004
#define CSR_ADJ   12100000            // 480000 ints

__device__ __forceinline__ float ldf(const void* p, long i, bool bf) {
  if (bf) return __bfloat162float(((const bf16*)p)[i]);
  return ((const float*)p)[i];
}

// ---------------- K0: detect input dtype from x ----------------
__global__ __launch_bounds__(64) void k_detect(const void* __restrict__ x, int* __restrict__ flag)
{
  int lane = threadIdx.x;
  unsigned w = ((const unsigned*)x)[lane];
  unsigned low = w & 0xFFFFu;
  unsigned el = (low >> 7) & 0xFFu;
  bool hit = (el >= 0x70u && el <= 0x86u);
  unsigned long long m = __ballot(hit);
  if (lane == 0) *flag = (__popcll(m) >= 32) ? 1 : 0;
}

// ---------------- CSR build ----------------
__global__ __launch_bounds__(256) void k_deg(const int* __restrict__ ei, int* __restrict__ deg)
{
  int i = blockIdx.x * 256 + threadIdx.x;
  if (i < NE) atomicAdd(&deg[ei[NE + i]], 1);
}

__global__ __launch_bounds__(1024) void k_scan(
    const int* __restrict__ deg, int* __restrict__ rowptr, int* __restrict__ cursor)
{
  __shared__ int buf[1024];
  __shared__ int carry;
  int tid = threadIdx.x;
  if (tid == 0) carry = 0;
  __syncthreads();
  for (int c = 0; c < 30; ++c) {
    int i = c * 1024 + tid;
    int v = (i < NN) ? deg[i] : 0;
    buf[tid] = v;
    __syncthreads();
    for (int off = 1; off < 1024; off <<= 1) {
      int t = (tid >= off) ? buf[tid - off] : 0;
      __syncthreads();
      buf[tid] += t;
      __syncthreads();
    }
    int excl = carry + buf[tid] - v;
    if (i < NN) { rowptr[i] = excl; cursor[i] = excl; }
    if (i == NN) rowptr[NN] = excl;
    __syncthreads();
    if (tid == 1023) carry += buf[1023];
    __syncthreads();
  }
}

__global__ __launch_bounds__(256) void k_fill(
    const int* __restrict__ ei, int* __restrict__ cursor, int* __restrict__ adj)
{
  int i = blockIdx.x * 256 + threadIdx.x;
  if (i < NE) {
    int p = atomicAdd(&cursor[ei[NE + i]], 1);
    adj[p] = i;
  }
}

// ---------------- K1: Q,K,V ----------------
__global__ __launch_bounds__(128) void k_qkv(
    const void* __restrict__ x, const void* __restrict__ Wq,
    const void* __restrict__ Wk, const void* __restrict__ Wv,
    float* __restrict__ Q, float* __restrict__ Kb, float* __restrict__ V,
    const int* __restrict__ flag)
{
  const bool isbf = (*flag != 0);
  __shared__ float xs[128][36];
  int tid = threadIdx.x;
  int row0 = blockIdx.x * 32;
  int nrows = min(32, NN - row0);
  for (int r = 0; r < 32; ++r)
    xs[tid][r] = (r < nrows) ? ldf(x, (long)(row0 + r) * DD + tid, isbf) : 0.f;
  __syncthreads();
  int c0 = (tid & 63) * 2;
  int rh = (tid >> 6) * 16;
  const void* Ws[3] = {Wq, Wk, Wv};
  float* Os[3] = {Q, Kb, V};
  for (int mm = 0; mm < 3; ++mm) {
    const void* W = Ws[mm];
    float u0[16], u1[16];
    #pragma unroll
    for (int r = 0; r < 16; ++r) { u0[r] = 0.f; u1[r] = 0.f; }
    #pragma unroll 4
    for (int k = 0; k < 128; ++k) {
      float w0 = ldf(W, (long)k * DD + c0, isbf);
      float w1 = ldf(W, (long)k * DD + c0 + 1, isbf);
      const float4* xp = (const float4*)&xs[k][rh];
      #pragma unroll
      for (int r4 = 0; r4 < 4; ++r4) {
        float4 x4 = xp[r4];
        u0[r4*4+0] += x4.x * w0; u1[r4*4+0] += x4.x * w1;
        u0[r4*4+1] += x4.y * w0; u1[r4*4+1] += x4.y * w1;
        u0[r4*4+2] += x4.z * w0; u1[r4*4+2] += x4.z * w1;
        u0[r4*4+3] += x4.w * w0; u1[r4*4+3] += x4.w * w1;
      }
    }
    float* O = Os[mm];
    #pragma unroll
    for (int r = 0; r < 16; ++r) {
      if (rh + r < nrows)
        *(float2*)&O[(long)(row0 + rh + r) * DD + c0] = make_float2(u0[r], u1[r]);
    }
  }
}

// ---------------- K2: per-edge scores (no z atomics) ----------------
__global__ __launch_bounds__(128) void k_edge_score(
    const int* __restrict__ ei, const void* __restrict__ ea,
    const void* __restrict__ We, const float* __restrict__ Q,
    const float* __restrict__ Kb,
    float* __restrict__ score, const int* __restrict__ flag)
{
  const bool isbf = (*flag != 0);
  __shared__ float es[64][36];
  __shared__ int sd_s[32], sd_d[32];
  int tid = threadIdx.x;
  long e0 = (long)blockIdx.x * 32;
  #pragma unroll
  for (int i = 0; i < 16; ++i) {
    int idx = i * 128 + tid;
    es[idx & 63][idx >> 6] = ldf(ea, e0 * ED + idx, isbf);
  }
  if (tid < 32) sd_s[tid] = ei[e0 + tid];
  else if (tid < 64) sd_d[tid - 32] = ei[NE + e0 + (tid - 32)];
  __syncthreads();
  float pe[32];
  #pragma unroll
  for (int r = 0; r < 32; ++r) pe[r] = 0.f;
  #pragma unroll 4
  for (int k = 0; k < 64; ++k) {
    float w = ldf(We, (long)k * DD + tid, isbf);
    const float4* ep = (const float4*)&es[k][0];
    #pragma unroll
    for (int r4 = 0; r4 < 8; ++r4) {
      float4 e4 = ep[r4];
      pe[r4*4+0] += e4.x * w; pe[r4*4+1] += e4.y * w;
      pe[r4*4+2] += e4.z * w; pe[r4*4+3] += e4.w * w;
    }
  }
  int h = tid >> 4;
  bool lead = (tid & 15) == 0;
  #pragma unroll 4
  for (int r = 0; r < 32; ++r) {
    int s = sd_s[r], d = sd_d[r];
    float q  = Q [(long)d * DD + tid];
    float kk = Kb[(long)s * DD + tid];
    float sv = q * kk * pe[r];
    sv += __shfl_xor(sv, 1);
    sv += __shfl_xor(sv, 2);
    sv += __shfl_xor(sv, 4);
    sv += __shfl_xor(sv, 8);
    if (lead) score[(e0 + r) * NH + h] = sv * 0.25f;
  }
}

// ---------------- K3: CSR aggregate — 1 wave/node, zero atomics ----------------
// h_attn[d] = (sum_e ec_e * V[s_e]) / (sum_e ec_e + 1e-6): the reference's
// z is the same sum (linearity), so normalize once at the end.
__global__ __launch_bounds__(256) void k_aggregate(
    const int* __restrict__ ei, const float* __restrict__ V,
    const float* __restrict__ score, const int* __restrict__ rowptr,
    const int* __restrict__ adj, float* __restrict__ hatt)
{
  int lane = threadIdx.x & 63;
  int wv = threadIdx.x >> 6;
  int d = blockIdx.x * 4 + wv;
  if (d >= NN) return;
  int p0 = rowptr[d], p1 = rowptr[d + 1];
  int hsh = lane >> 3;                  // head of dims 2*lane, 2*lane+1
  float a0 = 0.f, a1 = 0.f, zh = 0.f;
  for (int p = p0; p < p1; ++p) {
    int e = adj[p];                     // wave-uniform
    int s = ei[e];                      // wave-uniform
    float sc = score[(long)e * NH + hsh];
    float ec = __expf(fminf(fmaxf(sc, -5.f), 5.f));
    float2 v = *(const float2*)(V + (long)s * DD + 2 * lane);
    a0 += ec * v.x; a1 += ec * v.y; zh += ec;
  }
  float inv = 1.f / (zh + 1e-6f);
  *(float2*)(hatt + (long)d * DD + 2 * lane) = make_float2(a0 * inv, a1 * inv);
}

// ---------------- K4: edge projections + stats ----------------
__global__ __launch_bounds__(128) void k_edge_proj(
    const void* __restrict__ ea, const float* __restrict__ score,
    const void* __restrict__ W_ep, const void* __restrict__ b_ep,
    const void* __restrict__ W_Oe, const void* __restrict__ b_Oe,
    float* __restrict__ eout, float* __restrict__ stats,
    const int* __restrict__ flag)
{
  const bool isbf = (*flag != 0);
  __shared__ float sc[32][9];
  __shared__ float ep_lds[64][36];
  __shared__ float rs[2][64], rq[2][64];
  int tid = threadIdx.x;
  int j = tid & 63, wv = tid >> 6, rh = wv * 16;
  float bep = ldf(b_ep, j, isbf), boe = ldf(b_Oe, j, isbf);
  float wep[8];
  #pragma unroll
  for (int hh = 0; hh < 8; ++hh) wep[hh] = ldf(W_ep, hh * ED + j, isbf);
  float lsum = 0.f, lsq = 0.f;
  for (int t = blockIdx.x; t < NE / 32; t += gridDim.x) {
    long e0 = (long)t * 32;
    __syncthreads();
    #pragma unroll
    for (int i = 0; i < 2; ++i) {
      int idx = i * 128 + tid;
      sc[idx >> 3][idx & 7] = score[e0 * NH + idx];
    }
    __syncthreads();
    float u[16];
    #pragma unroll
    for (int r = 0; r < 16; ++r) u[r] = bep;
    #pragma unroll
    for (int hh = 0; hh < 8; ++hh) {
      float w = wep[hh];
      #pragma unroll
      for (int r = 0; r < 16; ++r) u[r] += sc[rh + r][hh] * w;
    }
    #pragma unroll
    for (int r = 0; r < 16; ++r) ep_lds[j][rh + r] = u[r];
    __syncthreads();
    float acc[16];
    #pragma unroll
    for (int r = 0; r < 16; ++r) acc[r] = 0.f;
    #pragma unroll 4
    for (int k = 0; k < 64; ++k) {
      float w = ldf(W_Oe, (long)k * ED + j, isbf);
      const float4* up = (const float4*)&ep_lds[k][rh];
      #pragma unroll
      for (int r4 = 0; r4 < 4; ++r4) {
        float4 u4 = up[r4];
        acc[r4*4+0] += u4.x * w; acc[r4*4+1] += u4.y * w;
        acc[r4*4+2] += u4.z * w; acc[r4*4+3] += u4.w * w;
      }
    }
    #pragma unroll
    for (int r = 0; r < 16; ++r) {
      float v = ldf(ea, (e0 + rh + r) * ED + j, isbf) + acc[r] + boe;
      eout[(e0 + rh + r) * ED + j] = v;
      lsum += v; lsq += v * v;
    }
  }
  rs[wv][j] = lsum; rq[wv][j] = lsq;
  __syncthreads();
  if (wv == 0) {
    atomicAdd(&stats[ST_SUM_E1 + j], rs[0][j] + rs[1][j]);
    atomicAdd(&stats[ST_SQ_E1 + j], rq[0][j] + rq[1][j]);
  }
}

// ---------------- K5: h projection + residual + stats ----------------
__global__ __launch_bounds__(128) void k_hproj(
    const float* __restrict__ hatt, const void* __restrict__ x,
    const void* __restrict__ W_Oh, const void* __restrict__ b_Oh,
    float* __restrict__ hout, float* __restrict__ stats,
    const int* __restrict__ flag)
{
  const bool isbf = (*flag != 0);
  __shared__ float hs[128][36];
  __shared__ float ssum[2][128], ssq[2][128];
  int tid = threadIdx.x;
  int row0 = blockIdx.x * 32;
  int nrows = min(32, NN - row0);
  for (int r = 0; r < 32; ++r)
    hs[tid][r] = (r < nrows) ? hatt[(long)(row0 + r) * DD + tid] : 0.f;
  __syncthreads();
  int c0 = (tid & 63) * 2;
  int wv = tid >> 6;
  int rh = wv * 16;
  float u0[16], u1[16];
  #pragma unroll
  for (int r = 0; r < 16; ++r) { u0[r] = 0.f; u1[r] = 0.f; }
  #pragma unroll 4
  for (int k = 0; k < 128; ++k) {
    float w0 = ldf(W_Oh, (long)k * DD + c0, isbf);
    float w1 = ldf(W_Oh, (long)k * DD + c0 + 1, isbf);
    const float4* hp = (const float4*)&hs[k][rh];
    #pragma unroll
    for (int r4 = 0; r4 < 4; ++r4) {
      float4 h4 = hp[r4];
      u0[r4*4+0] += h4.x * w0; u1[r4*4+0] += h4.x * w1;
      u0[r4*4+1] += h4.y * w0; u1[r4*4+1] += h4.y * w1;
      u0[r4*4+2] += h4.z * w0; u1[r4*4+2] += h4.z * w1;
      u0[r4*4+3] += h4.w * w0; u1[r4*4+3] += h4.w * w1;
    }
  }
  float bo0 = ldf(b_Oh, c0, isbf), bo1 = ldf(b_Oh, c0 + 1, isbf);
  float s0 = 0.f, q0 = 0.f, s1 = 0.f, q1 = 0.f;
  #pragma unroll
  for (int r = 0; r < 16; ++r) {
    if (rh + r < nrows) {
      long row = row0 + rh + r;
      float v0 = ldf(x, row * DD + c0, isbf) + u0[r] + bo0;
      float v1 = ldf(x, row * DD + c0 + 1, isbf) + u1[r] + bo1;
      *(float2*)&hout[row * DD + c0] = make_float2(v0, v1);
      s0 += v0; q0 += v0 * v0; s1 += v1; q1 += v1 * v1;
    }
  }
  ssum[wv][c0] = s0; ssum[wv][c0 + 1] = s1;
  ssq[wv][c0] = q0;  ssq[wv][c0 + 1] = q1;
  __syncthreads();
  atomicAdd(&stats[ST_SUM_H1 + tid], ssum[0][tid] + ssum[1][tid]);
  atomicAdd(&stats[ST_SQ_H1 + tid], ssq[0][tid] + ssq[1][tid]);
}

// ---------------- K6: h BN1 + FFN + residual + stats2 ----------------
__global__ __launch_bounds__(128) void k_hffn(
    float* __restrict__ hio,
    const void* __restrict__ g1h, const void* __restrict__ B1h,
    const void* __restrict__ W_h1, const void* __restrict__ b_h1,
    const void* __restrict__ W_h2, const void* __restrict__ b_h2,
    float* __restrict__ stats, const int* __restrict__ flag)
{
  const bool isbf = (*flag != 0);
  __shared__ float hb[128][36];
  __shared__ float uu[256][36];
  __shared__ float ssum[2][128], ssq[2][128];
  int tid = threadIdx.x;
  int row0 = blockIdx.x * 32;
  int nrows = min(32, NN - row0);
  float m = stats[ST_SUM_H1 + tid] * (1.0f / NN);
  float var = stats[ST_SQ_H1 + tid] * (1.0f / NN) - m * m;
  float rstd = rsqrtf(fmaxf(var, 0.f) + 1e-5f);
  float g = ldf(g1h, tid, isbf), B = ldf(B1h, tid, isbf);
  for (int r = 0; r < 32; ++r) {
    float v = (r < nrows) ? hio[(long)(row0 + r) * DD + tid] : 0.f;
    hb[tid][r] = g * (v - m) * rstd + B;
  }
  __syncthreads();
  float u0[32], u1[32];
  #pragma unroll
  for (int r = 0; r < 32; ++r) { u0[r] = 0.f; u1[r] = 0.f; }
  #pragma unroll 2
  for (int k = 0; k < 128; ++k) {
    float w0 = ldf(W_h1, (long)k * 256 + tid, isbf);
    float w1 = ldf(W_h1, (long)k * 256 + 128 + tid, isbf);
    const float4* hp = (const float4*)&hb[k][0];
    #pragma unroll
    for (int r4 = 0; r4 < 8; ++r4) {
      float4 h4 = hp[r4];
      u0[r4*4+0] += h4.x * w0; u1[r4*4+0] += h4.x * w1;
      u0[r4*4+1] += h4.y * w0; u1[r4*4+1] += h4.y * w1;
      u0[r4*4+2] += h4.z * w0; u1[r4*4+2] += h4.z * w1;
      u0[r4*4+3] += h4.w * w0; u1[r4*4+3] += h4.w * w1;
    }
  }
  float bu0 = ldf(b_h1, tid, isbf), bu1 = ldf(b_h1, 128 + tid, isbf);
  for (int r = 0; r < 32; ++r) {
    uu[tid][r]       = fmaxf(u0[r] + bu0, 0.f);
    uu[128 + tid][r] = fmaxf(u1[r] + bu1, 0.f);
  }
  __syncthreads();
  int c0 = (tid & 63) * 2;
  int wv2 = tid >> 6;
  int rh2 = wv2 * 16;
  float f0[16], f1[16];
  #pragma unroll
  for (int r = 0; r < 16; ++r) { f0[r] = 0.f; f1[r] = 0.f; }
  #pragma unroll 2
  for (int jj = 0; jj < 256; ++jj) {
    float w0 = ldf(W_h2, (long)jj * DD + c0, isbf);
    float w1 = ldf(W_h2, (long)jj * DD + c0 + 1, isbf);
    const float4* up = (const float4*)&uu[jj][rh2];
    #pragma unroll
    for (int r4 = 0; r4 < 4; ++r4) {
      float4 u4 = up[r4];
      f0[r4*4+0] += u4.x * w0; f1[r4*4+0] += u4.x * w1;
      f0[r4*4+1] += u4.y * w0; f1[r4*4+1] += u4.y * w1;
      f0[r4*4+2] += u4.z * w0; f1[r4*4+2] += u4.z * w1;
      f0[r4*4+3] += u4.w * w0; f1[r4*4+3] += u4.w * w1;
    }
  }
  float bf0 = ldf(b_h2, c0, isbf), bf1 = ldf(b_h2, c0 + 1, isbf);
  float s0 = 0.f, q0 = 0.f, s1 = 0.f, q1 = 0.f;
  #pragma unroll
  for (int r = 0; r < 16; ++r) {
    if (rh2 + r < nrows) {
      float t0 = hb[c0][rh2 + r] + f0[r] + bf0;
      float t1 = hb[c0 + 1][rh2 + r] + f1[r] + bf1;
      *(float2*)&hio[(long)(row0 + rh2 + r) * DD + c0] = make_float2(t0, t1);
      s0 += t0; q0 += t0 * t0; s1 += t1; q1 += t1 * t1;
    }
  }
  ssum[wv2][c0] = s0; ssum[wv2][c0 + 1] = s1;
  ssq[wv2][c0] = q0;  ssq[wv2][c0 + 1] = q1;
  __syncthreads();
  atomicAdd(&stats[ST_SUM_H2 + tid], ssum[0][tid] + ssum[1][tid]);
  atomicAdd(&stats[ST_SQ_H2 + tid], ssq[0][tid] + ssq[1][tid]);
}

// ---------------- K7: h final BN2 (float4) ----------------
__global__ __launch_bounds__(256) void k_hfinal(
    float* __restrict__ io, const void* __restrict__ g,
    const void* __restrict__ B, const float* __restrict__ stats,
    const int* __restrict__ flag)
{
  const bool isbf = (*flag != 0);
  long idx = ((long)blockIdx.x * 256 + threadIdx.x) * 4;   // grid 3750
  int c = (int)(idx & (DD - 1));
  float4 v = *(float4*)(io + idx);
  float o[4] = {v.x, v.y, v.z, v.w};
  #pragma unroll
  for (int j = 0; j < 4; ++j) {
    int cc = c + j;
    float m = stats[ST_SUM_H2 + cc] * (1.0f / NN);
    float var = stats[ST_SQ_H2 + cc] * (1.0f / NN) - m * m;
    float rstd = rsqrtf(fmaxf(var, 0.f) + 1e-5f);
    o[j] = ldf(g, cc, isbf) * (o[j] - m) * rstd + ldf(B, cc, isbf);
  }
  *(float4*)(io + idx) = make_float4(o[0], o[1], o[2], o[3]);
}

// ---------------- K8: e BN1 + FFN + residual + stats2 (v2, best measured) ----------------
__global__ __launch_bounds__(128) void k_effn(
    float* __restrict__ eio,
    const void* __restrict__ g1e, const void* __restrict__ B1e,
    const void* __restrict__ W_e1, const void* __restrict__ b_e1,
    const void* __restrict__ W_e2, const void* __restrict__ b_e2,
    float* __restrict__ stats, const int* __restrict__ flag)
{
  const bool isbf = (*flag != 0);
  __shared__ float es[64][36];
  __shared__ float uu[128][36];
  __shared__ float rs[2][64], rq[2][64];
  int tid = threadIdx.x;
  int f = tid & 63;
  int wv = tid >> 6;
  int rh = wv * 16;
  long row0 = (long)blockIdx.x * 32;
  float m = stats[ST_SUM_E1 + f] * (1.0f / NE);
  float var = stats[ST_SQ_E1 + f] * (1.0f / NE) - m * m;
  float rstd = rsqrtf(fmaxf(var, 0.f) + 1e-5f);
  float g = ldf(g1e, f, isbf), B = ldf(B1e, f, isbf);
  #pragma unroll
  for (int r = 0; r < 16; ++r) {
    float v = eio[(row0 + rh + r) * ED + f];
    es[f][rh + r] = g * (v - m) * rstd + B;
  }
  __syncthreads();
  float u[32];
  #pragma unroll
  for (int r = 0; r < 32; ++r) u[r] = 0.f;
  #pragma unroll 4
  for (int k = 0; k < 64; ++k) {
    float w = ldf(W_e1, (long)k * 128 + tid, isbf);
    const float4* ep = (const float4*)&es[k][0];
    #pragma unroll
    for (int r4 = 0; r4 < 8; ++r4) {
      float4 e4 = ep[r4];
      u[r4*4+0] += e4.x * w; u[r4*4+1] += e4.y * w;
      u[r4*4+2] += e4.z * w; u[r4*4+3] += e4.w * w;
    }
  }
  float bu = ldf(b_e1, tid, isbf);
  #pragma unroll
  for (int r = 0; r < 32; ++r) uu[tid][r] = fmaxf(u[r] + bu, 0.f);
  __syncthreads();
  float acc[16];
  #pragma unroll
  for (int r = 0; r < 16; ++r) acc[r] = 0.f;
  #pragma unroll 4
  for (int j = 0; j < 128; ++j) {
    float w = ldf(W_e2, (long)j * ED + f, isbf);
    const float4* up = (const float4*)&uu[j][rh];
    #pragma unroll
    for (int r4 = 0; r4 < 4; ++r4) {
      float4 u4 = up[r4];
      acc[r4*4+0] += u4.x * w; acc[r4*4+1] += u4.y * w;
      acc[r4*4+2] += u4.z * w; acc[r4*4+3] += u4.w * w;
    }
  }
  float bf2 = ldf(b_e2, f, isbf);
  float lsum = 0.f, lsq = 0.f;
  #pragma unroll
  for (int r = 0; r < 16; ++r) {
    float t = es[f][rh + r] + acc[r] + bf2;
    eio[(row0 + rh + r) * ED + f] = t;
    lsum += t; lsq += t * t;
  }
  rs[wv][f] = lsum; rq[wv][f] = lsq;
  __syncthreads();
  if (wv == 0) {
    atomicAdd(&stats[ST_SUM_E2 + f], rs[0][f] + rs[1][f]);
    atomicAdd(&stats[ST_SQ_E2 + f], rq[0][f] + rq[1][f]);
  }
}

// ---------------- K9: e final BN2 (float4) ----------------
__global__ __launch_bounds__(256) void k_efinal(
    float* __restrict__ io, const void* __restrict__ g,
    const void* __restrict__ B, const float* __restrict__ stats,
    const int* __restrict__ flag)
{
  const bool isbf = (*flag != 0);
  long idx = ((long)blockIdx.x * 256 + threadIdx.x) * 4;   // grid 30000
  int c = (int)(idx & (ED - 1));
  float4 v = *(float4*)(io + idx);
  float o[4] = {v.x, v.y, v.z, v.w};
  #pragma unroll
  for (int j = 0; j < 4; ++j) {
    int cc = c + j;
    float m = stats[ST_SUM_E2 + cc] * (1.0f / NE);
    float var = stats[ST_SQ_E2 + cc] * (1.0f / NE) - m * m;
    float rstd = rsqrtf(fmaxf(var, 0.f) + 1e-5f);
    o[j] = ldf(g, cc, isbf) * (o[j] - m) * rstd + ldf(B, cc, isbf);
  }
  *(float4*)(io + idx) = make_float4(o[0], o[1], o[2], o[3]);
}

extern "C" void kernel_launch(void* const* d_in, const int* in_sizes, int n_in,
                              void* d_out, int out_size, void* d_ws, size_t ws_size,
                              hipStream_t stream) {
  const void* x    = d_in[0];
  const int*  ei   = (const int*)d_in[1];
  const void* ea   = d_in[2];
  const void* Wq   = d_in[3];
  const void* Wk   = d_in[4];
  const void* Wv   = d_in[5];
  const void* We   = d_in[6];
  const void* W_Oh = d_in[7];
  const void* b_Oh = d_in[8];
  const void* W_ep = d_in[9];
  const void* b_ep = d_in[10];
  const void* W_Oe = d_in[11];
  const void* b_Oe = d_in[12];
  const void* W_h1 = d_in[13];
  const void* b_h1 = d_in[14];
  const void* W_h2 = d_in[15];
  const void* b_h2 = d_in[16];
  const void* W_e1 = d_in[17];
  const void* b_e1 = d_in[18];
  const void* W_e2 = d_in[19];
  const void* b_e2 = d_in[20];
  const void* g1h  = d_in[21];
  const void* B1h  = d_in[22];
  const void* g1e  = d_in[23];
  const void* B1e  = d_in[24];
  const void* g2h  = d_in[25];
  const void* B2h  = d_in[26];
  const void* g2e  = d_in[27];
  const void* B2e  = d_in[28];

  float* ws    = (float*)d_ws;
  float* stats = ws;
  int*   flag  = (int*)(ws + W_FLAG);
  float* hatt  = ws + W_HATT;         // in ws: safe from eout overwrite
  float* score = ws + W_SC;

  // d_out (34.56M floats):
  //  phase 1: Q [0,3.84M) Kb [3.84M,7.68M) V [7.68M,11.52M), CSR [12M,12.58M)
  //  phase 2: hout [0,3.84M), eout [3.84M,34.56M) overwrite all of phase 1
  float* out  = (float*)d_out;
  float* hout = out;
  float* eout = out + (size_t)NN * DD;
  float* Q    = out;
  float* Kb   = out + 3840000;
  float* V    = out + 7680000;
  int* deg    = (int*)out + CSR_DEG;
  int* rowptr = (int*)out + CSR_ROW;
  int* cursor = (int*)out + CSR_CUR;
  int* adj    = (int*)out + CSR_ADJ;

  hipMemsetAsync(ws, 0, 1024 * sizeof(float), stream);   // stats + flag
  hipMemsetAsync(deg, 0, NN * sizeof(int), stream);
  k_detect<<<1, 64, 0, stream>>>(x, flag);

  k_deg <<<1875, 256, 0, stream>>>(ei, deg);
  k_scan<<<1, 1024, 0, stream>>>(deg, rowptr, cursor);
  k_fill<<<1875, 256, 0, stream>>>(ei, cursor, adj);

  k_qkv<<<938, 128, 0, stream>>>(x, Wq, Wk, Wv, Q, Kb, V, flag);
  k_edge_score<<<15000, 128, 0, stream>>>(ei, ea, We, Q, Kb, score, flag);
  k_aggregate<<<7500, 256, 0, stream>>>(ei, V, score, rowptr, adj, hatt);
  k_edge_proj<<<2048, 128, 0, stream>>>(ea, score, W_ep, b_ep, W_Oe, b_Oe, eout, stats, flag);
  k_hproj<<<938, 128, 0, stream>>>(hatt, x, W_Oh, b_Oh, hout, stats, flag);
  k_hffn<<<938, 128, 0, stream>>>(hout, g1h, B1h, W_h1, b_h1, W_h2, b_h2, stats, flag);
  k_hfinal<<<3750, 256, 0, stream>>>(hout, g2h, B2h, stats, flag);
  k_effn<<<15000, 128, 0, stream>>>(eout, g1e, B1e, W_e1, b_e1, W_e2, b_e2, stats, flag);
  k_efinal<<<30000, 256, 0, stream>>>(eout, g2e, B2e, stats, flag);
}

// Round 11
// 1605.706 us; speedup vs baseline: 1.3740x; 1.1398x over previous
//
#include <hip/hip_runtime.h>
#include <hip/hip_bf16.h>

typedef __hip_bfloat16 bf16;
typedef __attribute__((ext_vector_type(8))) short short8v;
typedef __attribute__((ext_vector_type(4))) float f32x4;

#define NN 30000
#define NE 480000
#define DD 128
#define ED 64
#define NH 8

#define ST_SUM_H1 0
#define ST_SQ_H1  128
#define ST_SUM_H2 256
#define ST_SQ_H2  384
#define ST_SUM_E1 512
#define ST_SQ_E1  576
#define ST_SUM_E2 640
#define ST_SQ_E2  704
#define W_FLAG    768

#define W_W1T   1024                  // W_e1 transposed bf16 [128n][64k]: 4096 words
#define W_W2T   5120                  // W_e2 transposed bf16 [64n][128k]: 4096 words
#define W_HATT  241024                // hatt: N*128 f32 in ws (fully written, no memset)
#define W_SC    4081024               // score: E*8 f32 in ws

// d_out scratch (float offsets) — alive only until k_aggregate completes;
// eout [3.84M,34.56M) overwrites this AFTER aggregate (k_edge_proj onward).
#define CSR_DEG   12000000
#define CSR_ROW   12030000            // 30001 ints
#define CSR_CUR   12060004
#define CSR_ADJ   12100000            // 480000 ints

__device__ __forceinline__ float ldf(const void* p, long i, bool bf) {
  if (bf) return __bfloat162float(((const bf16*)p)[i]);
  return ((const float*)p)[i];
}

__device__ __forceinline__ unsigned short f2b(float f) {
  unsigned u = __float_as_uint(f);
  unsigned r = (u + 0x7FFFu + ((u >> 16) & 1u)) >> 16;   // RNE
  return (unsigned short)r;
}
__device__ __forceinline__ float b2f(unsigned short b) {
  return __uint_as_float(((unsigned)b) << 16);
}

// ---------------- K0: detect input dtype from x ----------------
__global__ __launch_bounds__(64) void k_detect(const void* __restrict__ x, int* __restrict__ flag)
{
  int lane = threadIdx.x;
  unsigned w = ((const unsigned*)x)[lane];
  unsigned low = w & 0xFFFFu;
  unsigned el = (low >> 7) & 0xFFu;
  bool hit = (el >= 0x70u && el <= 0x86u);
  unsigned long long m = __ballot(hit);
  if (lane == 0) *flag = (__popcll(m) >= 32) ? 1 : 0;
}

// ---------------- K0b: transpose W_e1/W_e2 to k-contiguous bf16 in ws ----------------
__global__ __launch_bounds__(256) void k_wprep(
    const void* __restrict__ W_e1, const void* __restrict__ W_e2,
    unsigned short* __restrict__ w1t, unsigned short* __restrict__ w2t,
    const int* __restrict__ flag)
{
  const bool isbf = (*flag != 0);
  int i = blockIdx.x * 256 + threadIdx.x;      // 16384 total (grid 64)
  if (i < 8192) {
    int k = i >> 7, n = i & 127;               // W_e1[k][n], k<64, n<128
    w1t[n * 64 + k] = f2b(ldf(W_e1, i, isbf));
  } else {
    int j = i - 8192;
    int k = j >> 6, n = j & 63;                // W_e2[k][n], k<128, n<64
    w2t[n * 128 + k] = f2b(ldf(W_e2, j, isbf));
  }
}

// ---------------- CSR build ----------------
__global__ __launch_bounds__(256) void k_deg(const int* __restrict__ ei, int* __restrict__ deg)
{
  int i = blockIdx.x * 256 + threadIdx.x;
  if (i < NE) atomicAdd(&deg[ei[NE + i]], 1);
}

__global__ __launch_bounds__(1024) void k_scan(
    const int* __restrict__ deg, int* __restrict__ rowptr, int* __restrict__ cursor)
{
  __shared__ int buf[1024];
  __shared__ int carry;
  int tid = threadIdx.x;
  if (tid == 0) carry = 0;
  __syncthreads();
  for (int c = 0; c < 30; ++c) {
    int i = c * 1024 + tid;
    int v = (i < NN) ? deg[i] : 0;
    buf[tid] = v;
    __syncthreads();
    for (int off = 1; off < 1024; off <<= 1) {
      int t = (tid >= off) ? buf[tid - off] : 0;
      __syncthreads();
      buf[tid] += t;
      __syncthreads();
    }
    int excl = carry + buf[tid] - v;
    if (i < NN) { rowptr[i] = excl; cursor[i] = excl; }
    if (i == NN) rowptr[NN] = excl;
    __syncthreads();
    if (tid == 1023) carry += buf[1023];
    __syncthreads();
  }
}

__global__ __launch_bounds__(256) void k_fill(
    const int* __restrict__ ei, int* __restrict__ cursor, int* __restrict__ adj)
{
  int i = blockIdx.x * 256 + threadIdx.x;
  if (i < NE) {
    int p = atomicAdd(&cursor[ei[NE + i]], 1);
    adj[p] = i;
  }
}

// ---------------- K1: Q,K,V ----------------
__global__ __launch_bounds__(128) void k_qkv(
    const void* __restrict__ x, const void* __restrict__ Wq,
    const void* __restrict__ Wk, const void* __restrict__ Wv,
    float* __restrict__ Q, float* __restrict__ Kb, float* __restrict__ V,
    const int* __restrict__ flag)
{
  const bool isbf = (*flag != 0);
  __shared__ float xs[128][36];
  int tid = threadIdx.x;
  int row0 = blockIdx.x * 32;
  int nrows = min(32, NN - row0);
  for (int r = 0; r < 32; ++r)
    xs[tid][r] = (r < nrows) ? ldf(x, (long)(row0 + r) * DD + tid, isbf) : 0.f;
  __syncthreads();
  int c0 = (tid & 63) * 2;
  int rh = (tid >> 6) * 16;
  const void* Ws[3] = {Wq, Wk, Wv};
  float* Os[3] = {Q, Kb, V};
  for (int mm = 0; mm < 3; ++mm) {
    const void* W = Ws[mm];
    float u0[16], u1[16];
    #pragma unroll
    for (int r = 0; r < 16; ++r) { u0[r] = 0.f; u1[r] = 0.f; }
    #pragma unroll 4
    for (int k = 0; k < 128; ++k) {
      float w0 = ldf(W, (long)k * DD + c0, isbf);
      float w1 = ldf(W, (long)k * DD + c0 + 1, isbf);
      const float4* xp = (const float4*)&xs[k][rh];
      #pragma unroll
      for (int r4 = 0; r4 < 4; ++r4) {
        float4 x4 = xp[r4];
        u0[r4*4+0] += x4.x * w0; u1[r4*4+0] += x4.x * w1;
        u0[r4*4+1] += x4.y * w0; u1[r4*4+1] += x4.y * w1;
        u0[r4*4+2] += x4.z * w0; u1[r4*4+2] += x4.z * w1;
        u0[r4*4+3] += x4.w * w0; u1[r4*4+3] += x4.w * w1;
      }
    }
    float* O = Os[mm];
    #pragma unroll
    for (int r = 0; r < 16; ++r) {
      if (rh + r < nrows)
        *(float2*)&O[(long)(row0 + rh + r) * DD + c0] = make_float2(u0[r], u1[r]);
    }
  }
}

// ---------------- K2: per-edge scores (no z atomics) ----------------
__global__ __launch_bounds__(128) void k_edge_score(
    const int* __restrict__ ei, const void* __restrict__ ea,
    const void* __restrict__ We, const float* __restrict__ Q,
    const float* __restrict__ Kb,
    float* __restrict__ score, const int* __restrict__ flag)
{
  const bool isbf = (*flag != 0);
  __shared__ float es[64][36];
  __shared__ int sd_s[32], sd_d[32];
  int tid = threadIdx.x;
  long e0 = (long)blockIdx.x * 32;
  #pragma unroll
  for (int i = 0; i < 16; ++i) {
    int idx = i * 128 + tid;
    es[idx & 63][idx >> 6] = ldf(ea, e0 * ED + idx, isbf);
  }
  if (tid < 32) sd_s[tid] = ei[e0 + tid];
  else if (tid < 64) sd_d[tid - 32] = ei[NE + e0 + (tid - 32)];
  __syncthreads();
  float pe[32];
  #pragma unroll
  for (int r = 0; r < 32; ++r) pe[r] = 0.f;
  #pragma unroll 4
  for (int k = 0; k < 64; ++k) {
    float w = ldf(We, (long)k * DD + tid, isbf);
    const float4* ep = (const float4*)&es[k][0];
    #pragma unroll
    for (int r4 = 0; r4 < 8; ++r4) {
      float4 e4 = ep[r4];
      pe[r4*4+0] += e4.x * w; pe[r4*4+1] += e4.y * w;
      pe[r4*4+2] += e4.z * w; pe[r4*4+3] += e4.w * w;
    }
  }
  int h = tid >> 4;
  bool lead = (tid & 15) == 0;
  #pragma unroll 4
  for (int r = 0; r < 32; ++r) {
    int s = sd_s[r], d = sd_d[r];
    float q  = Q [(long)d * DD + tid];
    float kk = Kb[(long)s * DD + tid];
    float sv = q * kk * pe[r];
    sv += __shfl_xor(sv, 1);
    sv += __shfl_xor(sv, 2);
    sv += __shfl_xor(sv, 4);
    sv += __shfl_xor(sv, 8);
    if (lead) score[(e0 + r) * NH + h] = sv * 0.25f;
  }
}

// ---------------- K3: CSR aggregate — 1 wave/node, zero atomics ----------------
__global__ __launch_bounds__(256) void k_aggregate(
    const int* __restrict__ ei, const float* __restrict__ V,
    const float* __restrict__ score, const int* __restrict__ rowptr,
    const int* __restrict__ adj, float* __restrict__ hatt)
{
  int lane = threadIdx.x & 63;
  int wv = threadIdx.x >> 6;
  int d = blockIdx.x * 4 + wv;
  if (d >= NN) return;
  int p0 = rowptr[d], p1 = rowptr[d + 1];
  int hsh = lane >> 3;
  float a0 = 0.f, a1 = 0.f, zh = 0.f;
  for (int p = p0; p < p1; ++p) {
    int e = adj[p];
    int s = ei[e];
    float sc = score[(long)e * NH + hsh];
    float ec = __expf(fminf(fmaxf(sc, -5.f), 5.f));
    float2 v = *(const float2*)(V + (long)s * DD + 2 * lane);
    a0 += ec * v.x; a1 += ec * v.y; zh += ec;
  }
  float inv = 1.f / (zh + 1e-6f);
  *(float2*)(hatt + (long)d * DD + 2 * lane) = make_float2(a0 * inv, a1 * inv);
}

// ---------------- K4: edge projections + stats ----------------
__global__ __launch_bounds__(128) void k_edge_proj(
    const void* __restrict__ ea, const float* __restrict__ score,
    const void* __restrict__ W_ep, const void* __restrict__ b_ep,
    const void* __restrict__ W_Oe, const void* __restrict__ b_Oe,
    float* __restrict__ eout, float* __restrict__ stats,
    const int* __restrict__ flag)
{
  const bool isbf = (*flag != 0);
  __shared__ float sc[32][9];
  __shared__ float ep_lds[64][36];
  __shared__ float rs[2][64], rq[2][64];
  int tid = threadIdx.x;
  int j = tid & 63, wv = tid >> 6, rh = wv * 16;
  float bep = ldf(b_ep, j, isbf), boe = ldf(b_Oe, j, isbf);
  float wep[8];
  #pragma unroll
  for (int hh = 0; hh < 8; ++hh) wep[hh] = ldf(W_ep, hh * ED + j, isbf);
  float lsum = 0.f, lsq = 0.f;
  for (int t = blockIdx.x; t < NE / 32; t += gridDim.x) {
    long e0 = (long)t * 32;
    __syncthreads();
    #pragma unroll
    for (int i = 0; i < 2; ++i) {
      int idx = i * 128 + tid;
      sc[idx >> 3][idx & 7] = score[e0 * NH + idx];
    }
    __syncthreads();
    float u[16];
    #pragma unroll
    for (int r = 0; r < 16; ++r) u[r] = bep;
    #pragma unroll
    for (int hh = 0; hh < 8; ++hh) {
      float w = wep[hh];
      #pragma unroll
      for (int r = 0; r < 16; ++r) u[r] += sc[rh + r][hh] * w;
    }
    #pragma unroll
    for (int r = 0; r < 16; ++r) ep_lds[j][rh + r] = u[r];
    __syncthreads();
    float acc[16];
    #pragma unroll
    for (int r = 0; r < 16; ++r) acc[r] = 0.f;
    #pragma unroll 4
    for (int k = 0; k < 64; ++k) {
      float w = ldf(W_Oe, (long)k * ED + j, isbf);
      const float4* up = (const float4*)&ep_lds[k][rh];
      #pragma unroll
      for (int r4 = 0; r4 < 4; ++r4) {
        float4 u4 = up[r4];
        acc[r4*4+0] += u4.x * w; acc[r4*4+1] += u4.y * w;
        acc[r4*4+2] += u4.z * w; acc[r4*4+3] += u4.w * w;
      }
    }
    #pragma unroll
    for (int r = 0; r < 16; ++r) {
      float v = ldf(ea, (e0 + rh + r) * ED + j, isbf) + acc[r] + boe;
      eout[(e0 + rh + r) * ED + j] = v;
      lsum += v; lsq += v * v;
    }
  }
  rs[wv][j] = lsum; rq[wv][j] = lsq;
  __syncthreads();
  if (wv == 0) {
    atomicAdd(&stats[ST_SUM_E1 + j], rs[0][j] + rs[1][j]);
    atomicAdd(&stats[ST_SQ_E1 + j], rq[0][j] + rq[1][j]);
  }
}

// ---------------- K5: h projection + residual + stats ----------------
__global__ __launch_bounds__(128) void k_hproj(
    const float* __restrict__ hatt, const void* __restrict__ x,
    const void* __restrict__ W_Oh, const void* __restrict__ b_Oh,
    float* __restrict__ hout, float* __restrict__ stats,
    const int* __restrict__ flag)
{
  const bool isbf = (*flag != 0);
  __shared__ float hs[128][36];
  __shared__ float ssum[2][128], ssq[2][128];
  int tid = threadIdx.x;
  int row0 = blockIdx.x * 32;
  int nrows = min(32, NN - row0);
  for (int r = 0; r < 32; ++r)
    hs[tid][r] = (r < nrows) ? hatt[(long)(row0 + r) * DD + tid] : 0.f;
  __syncthreads();
  int c0 = (tid & 63) * 2;
  int wv = tid >> 6;
  int rh = wv * 16;
  float u0[16], u1[16];
  #pragma unroll
  for (int r = 0; r < 16; ++r) { u0[r] = 0.f; u1[r] = 0.f; }
  #pragma unroll 4
  for (int k = 0; k < 128; ++k) {
    float w0 = ldf(W_Oh, (long)k * DD + c0, isbf);
    float w1 = ldf(W_Oh, (long)k * DD + c0 + 1, isbf);
    const float4* hp = (const float4*)&hs[k][rh];
    #pragma unroll
    for (int r4 = 0; r4 < 4; ++r4) {
      float4 h4 = hp[r4];
      u0[r4*4+0] += h4.x * w0; u1[r4*4+0] += h4.x * w1;
      u0[r4*4+1] += h4.y * w0; u1[r4*4+1] += h4.y * w1;
      u0[r4*4+2] += h4.z * w0; u1[r4*4+2] += h4.z * w1;
      u0[r4*4+3] += h4.w * w0; u1[r4*4+3] += h4.w * w1;
    }
  }
  float bo0 = ldf(b_Oh, c0, isbf), bo1 = ldf(b_Oh, c0 + 1, isbf);
  float s0 = 0.f, q0 = 0.f, s1 = 0.f, q1 = 0.f;
  #pragma unroll
  for (int r = 0; r < 16; ++r) {
    if (rh + r < nrows) {
      long row = row0 + rh + r;
      float v0 = ldf(x, row * DD + c0, isbf) + u0[r] + bo0;
      float v1 = ldf(x, row * DD + c0 + 1, isbf) + u1[r] + bo1;
      *(float2*)&hout[row * DD + c0] = make_float2(v0, v1);
      s0 += v0; q0 += v0 * v0; s1 += v1; q1 += v1 * v1;
    }
  }
  ssum[wv][c0] = s0; ssum[wv][c0 + 1] = s1;
  ssq[wv][c0] = q0;  ssq[wv][c0 + 1] = q1;
  __syncthreads();
  atomicAdd(&stats[ST_SUM_H1 + tid], ssum[0][tid] + ssum[1][tid]);
  atomicAdd(&stats[ST_SQ_H1 + tid], ssq[0][tid] + ssq[1][tid]);
}

// ---------------- K6: h BN1 + FFN + residual + stats2 ----------------
__global__ __launch_bounds__(128) void k_hffn(
    float* __restrict__ hio,
    const void* __restrict__ g1h, const void* __restrict__ B1h,
    const void* __restrict__ W_h1, const void* __restrict__ b_h1,
    const void* __restrict__ W_h2, const void* __restrict__ b_h2,
    float* __restrict__ stats, const int* __restrict__ flag)
{
  const bool isbf = (*flag != 0);
  __shared__ float hb[128][36];
  __shared__ float uu[256][36];
  __shared__ float ssum[2][128], ssq[2][128];
  int tid = threadIdx.x;
  int row0 = blockIdx.x * 32;
  int nrows = min(32, NN - row0);
  float m = stats[ST_SUM_H1 + tid] * (1.0f / NN);
  float var = stats[ST_SQ_H1 + tid] * (1.0f / NN) - m * m;
  float rstd = rsqrtf(fmaxf(var, 0.f) + 1e-5f);
  float g = ldf(g1h, tid, isbf), B = ldf(B1h, tid, isbf);
  for (int r = 0; r < 32; ++r) {
    float v = (r < nrows) ? hio[(long)(row0 + r) * DD + tid] : 0.f;
    hb[tid][r] = g * (v - m) * rstd + B;
  }
  __syncthreads();
  float u0[32], u1[32];
  #pragma unroll
  for (int r = 0; r < 32; ++r) { u0[r] = 0.f; u1[r] = 0.f; }
  #pragma unroll 2
  for (int k = 0; k < 128; ++k) {
    float w0 = ldf(W_h1, (long)k * 256 + tid, isbf);
    float w1 = ldf(W_h1, (long)k * 256 + 128 + tid, isbf);
    const float4* hp = (const float4*)&hb[k][0];
    #pragma unroll
    for (int r4 = 0; r4 < 8; ++r4) {
      float4 h4 = hp[r4];
      u0[r4*4+0] += h4.x * w0; u1[r4*4+0] += h4.x * w1;
      u0[r4*4+1] += h4.y * w0; u1[r4*4+1] += h4.y * w1;
      u0[r4*4+2] += h4.z * w0; u1[r4*4+2] += h4.z * w1;
      u0[r4*4+3] += h4.w * w0; u1[r4*4+3] += h4.w * w1;
    }
  }
  float bu0 = ldf(b_h1, tid, isbf), bu1 = ldf(b_h1, 128 + tid, isbf);
  for (int r = 0; r < 32; ++r) {
    uu[tid][r]       = fmaxf(u0[r] + bu0, 0.f);
    uu[128 + tid][r] = fmaxf(u1[r] + bu1, 0.f);
  }
  __syncthreads();
  int c0 = (tid & 63) * 2;
  int wv2 = tid >> 6;
  int rh2 = wv2 * 16;
  float f0[16], f1[16];
  #pragma unroll
  for (int r = 0; r < 16; ++r) { f0[r] = 0.f; f1[r] = 0.f; }
  #pragma unroll 2
  for (int jj = 0; jj < 256; ++jj) {
    float w0 = ldf(W_h2, (long)jj * DD + c0, isbf);
    float w1 = ldf(W_h2, (long)jj * DD + c0 + 1, isbf);
    const float4* up = (const float4*)&uu[jj][rh2];
    #pragma unroll
    for (int r4 = 0; r4 < 4; ++r4) {
      float4 u4 = up[r4];
      f0[r4*4+0] += u4.x * w0; f1[r4*4+0] += u4.x * w1;
      f0[r4*4+1] += u4.y * w0; f1[r4*4+1] += u4.y * w1;
      f0[r4*4+2] += u4.z * w0; f1[r4*4+2] += u4.z * w1;
      f0[r4*4+3] += u4.w * w0; f1[r4*4+3] += u4.w * w1;
    }
  }
  float bf0 = ldf(b_h2, c0, isbf), bf1 = ldf(b_h2, c0 + 1, isbf);
  float s0 = 0.f, q0 = 0.f, s1 = 0.f, q1 = 0.f;
  #pragma unroll
  for (int r = 0; r < 16; ++r) {
    if (rh2 + r < nrows) {
      float t0 = hb[c0][rh2 + r] + f0[r] + bf0;
      float t1 = hb[c0 + 1][rh2 + r] + f1[r] + bf1;
      *(float2*)&hio[(long)(row0 + rh2 + r) * DD + c0] = make_float2(t0, t1);
      s0 += t0; q0 += t0 * t0; s1 += t1; q1 += t1 * t1;
    }
  }
  ssum[wv2][c0] = s0; ssum[wv2][c0 + 1] = s1;
  ssq[wv2][c0] = q0;  ssq[wv2][c0 + 1] = q1;
  __syncthreads();
  atomicAdd(&stats[ST_SUM_H2 + tid], ssum[0][tid] + ssum[1][tid]);
  atomicAdd(&stats[ST_SQ_H2 + tid], ssq[0][tid] + ssq[1][tid]);
}

// ---------------- K7: h final BN2 (float4) ----------------
__global__ __launch_bounds__(256) void k_hfinal(
    float* __restrict__ io, const void* __restrict__ g,
    const void* __restrict__ B, const float* __restrict__ stats,
    const int* __restrict__ flag)
{
  const bool isbf = (*flag != 0);
  long idx = ((long)blockIdx.x * 256 + threadIdx.x) * 4;   // grid 3750
  int c = (int)(idx & (DD - 1));
  float4 v = *(float4*)(io + idx);
  float o[4] = {v.x, v.y, v.z, v.w};
  #pragma unroll
  for (int j = 0; j < 4; ++j) {
    int cc = c + j;
    float m = stats[ST_SUM_H2 + cc] * (1.0f / NN);
    float var = stats[ST_SQ_H2 + cc] * (1.0f / NN) - m * m;
    float rstd = rsqrtf(fmaxf(var, 0.f) + 1e-5f);
    o[j] = ldf(g, cc, isbf) * (o[j] - m) * rstd + ldf(B, cc, isbf);
  }
  *(float4*)(io + idx) = make_float4(o[0], o[1], o[2], o[3]);
}

// ---------------- K8: e BN1 + FFN via bf16 MFMA (v6) ----------------
// 64 edges/block, 256 threads (4 waves). Wave w owns the 16-row M-stripe
// 16w..16w+15. All LDS tiles bf16 with XOR swizzle elem ^= ((row&7)<<3)
// (16B-granular -> b128 frag reads stay contiguous; 2-way bank alias = free).
// Fragment layouts (16x16x32): A: m=l&15, k=(l>>4)*8+j; B: n=l&15, same k;
// C/D: row=(l>>4)*4+reg, col=l&15 [m89-verified].
__global__ __launch_bounds__(256) void k_effn(
    float* __restrict__ eio,
    const void* __restrict__ g1e, const void* __restrict__ B1e,
    const unsigned short* __restrict__ w1t, const unsigned short* __restrict__ w2t,
    const void* __restrict__ b_e1, const void* __restrict__ b_e2,
    float* __restrict__ stats, const int* __restrict__ flag)
{
  const bool isbf = (*flag != 0);
  __shared__ unsigned short es[64 * 64];     // bn1 out  [edge][feat]   8KB
  __shared__ unsigned short uu[64 * 128];    // relu hid [edge][hid]   16KB
  __shared__ unsigned short w1[128 * 64];    // W1t      [n][k]        16KB
  __shared__ unsigned short w2[64 * 128];    // W2t      [n][k]        16KB
  __shared__ float ssum[4][64], ssq[4][64];
  int tid = threadIdx.x;
  int lane = tid & 63, w = tid >> 6;
  int ml = lane & 15, kg = lane >> 4;
  long e0 = (long)blockIdx.x * 64;           // NE = 64 * 7500 exactly
  // ---- stage W1t (4096 u32): k2 = (tid&31)*2 const per thread ----
  {
    unsigned* du = (unsigned*)w1;
    int k2 = (tid & 31) * 2;
    #pragma unroll
    for (int it = 0; it < 16; ++it) {
      int widx = it * 256 + tid;
      int n = widx >> 5;
      unsigned v = ((const unsigned*)w1t)[widx];
      du[(n * 64 + (k2 ^ ((n & 7) << 3))) >> 1] = v;
    }
  }
  // ---- stage W2t (4096 u32): k2 = (tid&63)*2 const ----
  {
    unsigned* du = (unsigned*)w2;
    int k2 = (tid & 63) * 2;
    #pragma unroll
    for (int it = 0; it < 16; ++it) {
      int widx = it * 256 + tid;
      int n = widx >> 6;
      unsigned v = ((const unsigned*)w2t)[widx];
      du[(n * 128 + (k2 ^ ((n & 7) << 3))) >> 1] = v;
    }
  }
  // ---- stage es: BN1(eio) -> bf16, cols (c2,c2+1) const per thread ----
  {
    unsigned* du = (unsigned*)es;
    int c2 = (tid & 31) * 2;
    float m0 = stats[ST_SUM_E1 + c2] * (1.0f / NE);
    float v0 = stats[ST_SQ_E1 + c2] * (1.0f / NE) - m0 * m0;
    float r0 = rsqrtf(fmaxf(v0, 0.f) + 1e-5f);
    float g0 = ldf(g1e, c2, isbf), B0 = ldf(B1e, c2, isbf);
    float m1 = stats[ST_SUM_E1 + c2 + 1] * (1.0f / NE);
    float v1 = stats[ST_SQ_E1 + c2 + 1] * (1.0f / NE) - m1 * m1;
    float r1 = rsqrtf(fmaxf(v1, 0.f) + 1e-5f);
    float g1 = ldf(g1e, c2 + 1, isbf), B1 = ldf(B1e, c2 + 1, isbf);
    #pragma unroll
    for (int it = 0; it < 8; ++it) {
      int widx = it * 256 + tid;           // 2048 u32 slots
      int r = widx >> 5;
      float2 v = *(const float2*)(eio + (e0 + r) * 64 + c2);
      unsigned short b0 = f2b(g0 * (v.x - m0) * r0 + B0);
      unsigned short b1 = f2b(g1 * (v.y - m1) * r1 + B1);
      du[(r * 64 + (c2 ^ ((r & 7) << 3))) >> 1] = (unsigned)b0 | ((unsigned)b1 << 16);
    }
  }
  __syncthreads();
  // ---- GEMM1: C1[16 x 128] = es[16w..][64] @ W1[64][128], wave-private M ----
  short8v a1[2];
  #pragma unroll
  for (int kt = 0; kt < 2; ++kt) {
    int row = w * 16 + ml;
    a1[kt] = *(short8v*)&es[row * 64 + ((kt * 32 + kg * 8) ^ ((row & 7) << 3))];
  }
  f32x4 acc1[8];
  #pragma unroll
  for (int nt = 0; nt < 8; ++nt) acc1[nt] = (f32x4){0.f, 0.f, 0.f, 0.f};
  #pragma unroll
  for (int nt = 0; nt < 8; ++nt) {
    #pragma unroll
    for (int kt = 0; kt < 2; ++kt) {
      int n = nt * 16 + ml;
      short8v b = *(short8v*)&w1[n * 64 + ((kt * 32 + kg * 8) ^ ((n & 7) << 3))];
      acc1[nt] = __builtin_amdgcn_mfma_f32_16x16x32_bf16(a1[kt], b, acc1[nt], 0, 0, 0);
    }
  }
  // relu + bias -> uu (wave-private rows: no barrier needed)
  #pragma unroll
  for (int nt = 0; nt < 8; ++nt) {
    float bb = ldf(b_e1, nt * 16 + ml, isbf);
    #pragma unroll
    for (int rg = 0; rg < 4; ++rg) {
      int row = w * 16 + kg * 4 + rg;
      int col = nt * 16 + ml;
      uu[row * 128 + (col ^ ((row & 7) << 3))] = f2b(fmaxf(acc1[nt][rg] + bb, 0.f));
    }
  }
  // ---- GEMM2: C2[16 x 64] = uu[16w..][128] @ W2[128][64] ----
  short8v a2[4];
  #pragma unroll
  for (int kt = 0; kt < 4; ++kt) {
    int row = w * 16 + ml;
    a2[kt] = *(short8v*)&uu[row * 128 + ((kt * 32 + kg * 8) ^ ((row & 7) << 3))];
  }
  f32x4 acc2[4];
  #pragma unroll
  for (int nt = 0; nt < 4; ++nt) acc2[nt] = (f32x4){0.f, 0.f, 0.f, 0.f};
  #pragma unroll
  for (int nt = 0; nt < 4; ++nt) {
    #pragma unroll
    for (int kt = 0; kt < 4; ++kt) {
      int n = nt * 16 + ml;
      short8v b = *(short8v*)&w2[n * 128 + ((kt * 32 + kg * 8) ^ ((n & 7) << 3))];
      acc2[nt] = __builtin_amdgcn_mfma_f32_16x16x32_bf16(a2[kt], b, acc2[nt], 0, 0, 0);
    }
  }
  // ---- epilogue: residual (bn1 bf16) + bias, store, stats ----
  #pragma unroll
  for (int nt = 0; nt < 4; ++nt) {
    int col = nt * 16 + ml;
    float bb = ldf(b_e2, col, isbf);
    float s = 0.f, q = 0.f;
    #pragma unroll
    for (int rg = 0; rg < 4; ++rg) {
      int row = w * 16 + kg * 4 + rg;
      float resv = b2f(es[row * 64 + (col ^ ((row & 7) << 3))]);
      float t = resv + acc2[nt][rg] + bb;
      eio[(e0 + row) * 64 + col] = t;
      s += t; q += t * t;
    }
    s += __shfl_xor(s, 16); s += __shfl_xor(s, 32);
    q += __shfl_xor(q, 16); q += __shfl_xor(q, 32);
    if (kg == 0) { ssum[w][col] = s; ssq[w][col] = q; }
  }
  __syncthreads();
  if (tid < 64) {
    atomicAdd(&stats[ST_SUM_E2 + tid], ssum[0][tid] + ssum[1][tid] + ssum[2][tid] + ssum[3][tid]);
    atomicAdd(&stats[ST_SQ_E2 + tid],  ssq[0][tid] + ssq[1][tid] + ssq[2][tid] + ssq[3][tid]);
  }
}

// ---------------- K9: e final BN2 (float4) ----------------
__global__ __launch_bounds__(256) void k_efinal(
    float* __restrict__ io, const void* __restrict__ g,
    const void* __restrict__ B, const float* __restrict__ stats,
    const int* __restrict__ flag)
{
  const bool isbf = (*flag != 0);
  long idx = ((long)blockIdx.x * 256 + threadIdx.x) * 4;   // grid 30000
  int c = (int)(idx & (ED - 1));
  float4 v = *(float4*)(io + idx);
  float o[4] = {v.x, v.y, v.z, v.w};
  #pragma unroll
  for (int j = 0; j < 4; ++j) {
    int cc = c + j;
    float m = stats[ST_SUM_E2 + cc] * (1.0f / NE);
    float var = stats[ST_SQ_E2 + cc] * (1.0f / NE) - m * m;
    float rstd = rsqrtf(fmaxf(var, 0.f) + 1e-5f);
    o[j] = ldf(g, cc, isbf) * (o[j] - m) * rstd + ldf(B, cc, isbf);
  }
  *(float4*)(io + idx) = make_float4(o[0], o[1], o[2], o[3]);
}

extern "C" void kernel_launch(void* const* d_in, const int* in_sizes, int n_in,
                              void* d_out, int out_size, void* d_ws, size_t ws_size,
                              hipStream_t stream) {
  const void* x    = d_in[0];
  const int*  ei   = (const int*)d_in[1];
  const void* ea   = d_in[2];
  const void* Wq   = d_in[3];
  const void* Wk   = d_in[4];
  const void* Wv   = d_in[5];
  const void* We   = d_in[6];
  const void* W_Oh = d_in[7];
  const void* b_Oh = d_in[8];
  const void* W_ep = d_in[9];
  const void* b_ep = d_in[10];
  const void* W_Oe = d_in[11];
  const void* b_Oe = d_in[12];
  const void* W_h1 = d_in[13];
  const void* b_h1 = d_in[14];
  const void* W_h2 = d_in[15];
  const void* b_h2 = d_in[16];
  const void* W_e1 = d_in[17];
  const void* b_e1 = d_in[18];
  const void* W_e2 = d_in[19];
  const void* b_e2 = d_in[20];
  const void* g1h  = d_in[21];
  const void* B1h  = d_in[22];
  const void* g1e  = d_in[23];
  const void* B1e  = d_in[24];
  const void* g2h  = d_in[25];
  const void* B2h  = d_in[26];
  const void* g2e  = d_in[27];
  const void* B2e  = d_in[28];

  float* ws    = (float*)d_ws;
  float* stats = ws;
  int*   flag  = (int*)(ws + W_FLAG);
  unsigned short* w1t = (unsigned short*)(ws + W_W1T);
  unsigned short* w2t = (unsigned short*)(ws + W_W2T);
  float* hatt  = ws + W_HATT;
  float* score = ws + W_SC;

  // d_out (34.56M floats):
  //  phase 1: Q [0,3.84M) Kb [3.84M,7.68M) V [7.68M,11.52M), CSR [12M,12.58M)
  //  phase 2: hout [0,3.84M), eout [3.84M,34.56M) overwrite all of phase 1
  float* out  = (float*)d_out;
  float* hout = out;
  float* eout = out + (size_t)NN * DD;
  float* Q    = out;
  float* Kb   = out + 3840000;
  float* V    = out + 7680000;
  int* deg    = (int*)out + CSR_DEG;
  int* rowptr = (int*)out + CSR_ROW;
  int* cursor = (int*)out + CSR_CUR;
  int* adj    = (int*)out + CSR_ADJ;

  hipMemsetAsync(ws, 0, 1024 * sizeof(float), stream);   // stats + flag
  hipMemsetAsync(deg, 0, NN * sizeof(int), stream);
  k_detect<<<1, 64, 0, stream>>>(x, flag);
  k_wprep<<<64, 256, 0, stream>>>(W_e1, W_e2, w1t, w2t, flag);

  k_deg <<<1875, 256, 0, stream>>>(ei, deg);
  k_scan<<<1, 1024, 0, stream>>>(deg, rowptr, cursor);
  k_fill<<<1875, 256, 0, stream>>>(ei, cursor, adj);

  k_qkv<<<938, 128, 0, stream>>>(x, Wq, Wk, Wv, Q, Kb, V, flag);
  k_edge_score<<<15000, 128, 0, stream>>>(ei, ea, We, Q, Kb, score, flag);
  k_aggregate<<<7500, 256, 0, stream>>>(ei, V, score, rowptr, adj, hatt);
  k_edge_proj<<<2048, 128, 0, stream>>>(ea, score, W_ep, b_ep, W_Oe, b_Oe, eout, stats, flag);
  k_hproj<<<938, 128, 0, stream>>>(hatt, x, W_Oh, b_Oh, hout, stats, flag);
  k_hffn<<<938, 128, 0, stream>>>(hout, g1h, B1h, W_h1, b_h1, W_h2, b_h2, stats, flag);
  k_hfinal<<<3750, 256, 0, stream>>>(hout, g2h, B2h, stats, flag);
  k_effn<<<7500, 256, 0, stream>>>(eout, g1e, B1e, w1t, w2t, b_e1, b_e2, stats, flag);
  k_efinal<<<30000, 256, 0, stream>>>(eout, g2e, B2e, stats, flag);
}